// Round 8
// baseline (4212.440 us; speedup 1.0000x reference)
//
#include <hip/hip_runtime.h>
#include <hip/hip_bf16.h>

// Problem constants
#define SEQL 4096
#define VECT 300
#define DP   320     // padded feature dim (k-dim), 10 chunks of 32
#define NQT  20      // n-tiles (320 cols) for projection GEMMs
#define HN   128
#define G3   384     // 3*H
#define JC   4       // flash j-chunks (split-K over key dim)

typedef unsigned short u16;
typedef unsigned char  u8;
typedef unsigned int   u32;
typedef __attribute__((ext_vector_type(8))) short bf16x8;  // 8 bf16 = 4 VGPRs
typedef __attribute__((ext_vector_type(4))) float f32x4;
typedef __attribute__((ext_vector_type(8))) int   v8i;     // 8 dwords (fp8 x32)

#define AS1 __attribute__((address_space(1)))
#define AS3 __attribute__((address_space(3)))

#define MFMA(a,b,c) __builtin_amdgcn_mfma_f32_16x16x32_bf16(a,b,c,0,0,0)
// Verified layouts (learn_hip m89/m91/m120):
//   A[m][k]: m=lane&15, k=(lane>>4)*8+j
//   B[k][n]: n=lane&15, k=(lane>>4)*8+j
//   C/D[row][col]: col=lane&15, row=(lane>>4)*4+reg

#define L2E 1.44269504088896f

__device__ __forceinline__ float bf2f(u16 v){
    union { unsigned u; float f; } t; t.u = ((unsigned)v) << 16; return t.f;
}
__device__ __forceinline__ u16 f2bf(float f){
    union { float f; unsigned u; } t; t.f = f;
    return (u16)((t.u + 0x7FFFu + ((t.u >> 16) & 1u)) >> 16);
}
__device__ __forceinline__ float sigm_f(float x){
    return __builtin_amdgcn_rcpf(1.f + __builtin_amdgcn_exp2f(-L2E * x));
}
__device__ __forceinline__ float tanh_f(float x){
    return fmaf(2.f, __builtin_amdgcn_rcpf(1.f + __builtin_amdgcn_exp2f(-2.f * L2E * x)), -1.f);
}

// ---------------- fp32 [R][C] -> bf16 padded [Rp][Cp], optional scale
__global__ __launch_bounds__(256) void cvt_pad(const float* __restrict__ src,
                                               u16* __restrict__ dst,
                                               int R, int C, int Rp, int Cp, float scale)
{
    int n = Rp * Cp;
    for (int i = blockIdx.x * blockDim.x + threadIdx.x; i < n; i += gridDim.x * blockDim.x){
        int r = i / Cp, c = i - r * Cp;
        float v = (r < R && c < C) ? src[r * C + c] * scale : 0.f;
        dst[i] = f2bf(v);
    }
}

// ---------------- fp32 -> fp8 e4m3 (pairs), n even
__global__ __launch_bounds__(256) void cvt_fp8(const float* __restrict__ src,
                                               u8* __restrict__ dst, int n)
{
    int i = (blockIdx.x * blockDim.x + threadIdx.x) * 2;
    if (i < n){
        int pk = __builtin_amdgcn_cvt_pk_fp8_f32(src[i], src[i + 1], 0, false);
        *(u16*)(dst + i) = (u16)(pk & 0xFFFF);
    }
}

// ---------------- fp32 vector scale-copy
__global__ __launch_bounds__(256) void scale_copy(const float* __restrict__ src,
                                                  float* __restrict__ dst, int n, float scale)
{
    int i = blockIdx.x * blockDim.x + threadIdx.x;
    if (i < n) dst[i] = src[i] * scale;
}

// ---------------- x: fp32 [S][300] -> XF fp32 [S][320] + CUR bf16 [S][320]
__global__ __launch_bounds__(256) void pad_x(const float* __restrict__ src,
                                             float* __restrict__ xf, u16* __restrict__ cur)
{
    int n = SEQL * DP;
    for (int i = blockIdx.x * blockDim.x + threadIdx.x; i < n; i += gridDim.x * blockDim.x){
        int r = i / DP, c = i - r * DP;
        float v = (c < VECT) ? src[r * VECT + c] : 0.f;
        xf[i]  = v;
        cur[i] = f2bf(v);
    }
}

// ---------------- GEMM: Y[s][i][col] = sum_d A[s][i][d] * W[wsel][col][d] + bias[col]
// 256 thr = 4 waves; wave handles 16 rows; WG = 64 rows.
// OM: 1 = fp32 row-major; 3 = QKV fused: slices 0,1 bf16 row-major, slice 2 bf16 transposed.
template<int NT, int OM, bool WPERSEQ>
__global__ __launch_bounds__(256) void gemm_k(
    const u16* __restrict__ A, const u16* __restrict__ Wp,
    const float* __restrict__ b0, const float* __restrict__ b1, const float* __restrict__ b2,
    int nb, void* __restrict__ Out)
{
    const int lane = threadIdx.x & 63;
    const int wid  = threadIdx.x >> 6;
    const int s    = blockIdx.z;
    const int sl   = blockIdx.y;
    const int wsel = WPERSEQ ? s : sl;
    const int row0 = blockIdx.x * 64 + wid * 16;
    const int m    = lane & 15;
    const int q    = lane >> 4;

    const u16* Arow = A + ((long)s * SEQL + row0) * DP;
    const u16* W    = Wp + (long)wsel * (NT * 16) * DP;

    f32x4 zf = {0.f, 0.f, 0.f, 0.f};
    f32x4 acc[NT];
    #pragma unroll
    for (int n = 0; n < NT; n++) acc[n] = zf;

    for (int c = 0; c < DP / 32; ++c){
        const int koff = c * 32 + q * 8;
        bf16x8 a0 = *(const bf16x8*)(Arow + m * DP + koff);
        #pragma unroll
        for (int n = 0; n < NT; n++){
            bf16x8 b = *(const bf16x8*)(W + (n * 16 + m) * DP + koff);
            acc[n] = MFMA(a0, b, acc[n]);
        }
    }

    const int bsel = WPERSEQ ? s : sl;
    const float* bp = (bsel == 0) ? b0 : ((bsel == 1) ? b1 : b2);
    const long SLC = 2L * SEQL * DP;  // per-slice stride in QKV buffer

    #pragma unroll
    for (int n = 0; n < NT; n++){
        int col = n * 16 + m;
        float bv = (col < nb) ? bp[col] : 0.f;
        #pragma unroll
        for (int r = 0; r < 4; r++){
            long row = row0 + q * 4 + r;
            float v = acc[n][r] + bv;
            if (OM == 1){
                long off = ((long)s * SEQL + row) * (long)(NT * 16) + col;
                ((float*)Out)[off] = v;
            } else {  // OM == 3
                long off;
                if (sl < 2) off = ((long)(sl * 2 + s) * SEQL + row) * DP + col;
                else        off = 2 * SLC + ((long)s * DP + col) * SEQL + row;
                ((u16*)Out)[off] = f2bf(v);
            }
        }
    }
}

// ---------------- flash attention chunk: Onum = exp(QK^T*scale - 16) V (unnormalized),
// Lp = row sums. Linear grid 512 = 64 xi * 8 combos; combo = bid&7 -> (jc,s) so that
// round-robin XCD dispatch puts all WGs sharing one K/VT chunk on one XCD (L2 reuse).
__global__ __launch_bounds__(256) void flash_k(
    const u16* __restrict__ Q, const u16* __restrict__ K, const u16* __restrict__ VT,
    u16* __restrict__ Onum, float* __restrict__ Lp)
{
    const int lane = threadIdx.x & 63;
    const int wid  = threadIdx.x >> 6;
    const int bid  = blockIdx.x;
    const int s    = bid & 1;
    const int jc   = (bid >> 1) & 3;
    const int xi   = bid >> 3;
    const int row0 = xi * 64 + wid * 16;
    const int m = lane & 15, q = lane >> 4;

    __shared__ __align__(16) u16 pbuf_all[4][16 * 72];
    u16* pbuf = pbuf_all[wid];

    const u16* Qb  = Q  + ((long)s * SEQL + row0) * DP;
    const u16* Kb  = K  + (long)s * SEQL * DP;
    const u16* VTb = VT + (long)s * DP * SEQL;

    bf16x8 qf[10];
    #pragma unroll
    for (int c = 0; c < 10; c++)
        qf[c] = *(const bf16x8*)(Qb + m * DP + c * 32 + q * 8);

    f32x4 zf = {0.f, 0.f, 0.f, 0.f};
    f32x4 oacc[NQT];
    #pragma unroll
    for (int n = 0; n < NQT; n++) oacc[n] = zf;
    float lacc[4] = {0.f, 0.f, 0.f, 0.f};

    const float K2 = 0.057735026918962576f * L2E;  // scale * log2(e)
    const float MB = -16.f * L2E;                   // fixed max offset (scores bounded ~|4|)

    for (int j = jc * 32; j < jc * 32 + 32; ++j){
        f32x4 sA = zf, sB = zf;
        #pragma unroll
        for (int c = 0; c < 10; c++){
            const int koff = c * 32 + q * 8;
            bf16x8 kA = *(const bf16x8*)(Kb + (long)(j * 32 +      m) * DP + koff);
            bf16x8 kB = *(const bf16x8*)(Kb + (long)(j * 32 + 16 + m) * DP + koff);
            sA = MFMA(qf[c], kA, sA);
            sB = MFMA(qf[c], kB, sB);
        }
        #pragma unroll
        for (int r = 0; r < 4; r++){
            float a = __builtin_amdgcn_exp2f(fmaf(sA[r], K2, MB));
            float b = __builtin_amdgcn_exp2f(fmaf(sB[r], K2, MB));
            lacc[r] += a + b;
            pbuf[(q * 4 + r) * 72 +      m] = f2bf(a);
            pbuf[(q * 4 + r) * 72 + 16 + m] = f2bf(b);
        }
        asm volatile("s_waitcnt lgkmcnt(0)" ::: "memory");
        bf16x8 pf = *(const bf16x8*)(pbuf + m * 72 + q * 8);

        #pragma unroll
        for (int n = 0; n < NQT; n++){
            bf16x8 vb = *(const bf16x8*)(VTb + (long)(n * 16 + m) * SEQL + j * 32 + q * 8);
            oacc[n] = MFMA(pf, vb, oacc[n]);
        }
    }

    // reduce l over the 16 m-lanes (columns)
    #pragma unroll
    for (int r = 0; r < 4; r++){
        float t = lacc[r];
        t += __shfl_xor(t, 1); t += __shfl_xor(t, 2);
        t += __shfl_xor(t, 4); t += __shfl_xor(t, 8);
        lacc[r] = t;
    }
    const long grow0 = (long)s * SEQL + row0;   // global row base (0..2S)
    if (m == 0){
        #pragma unroll
        for (int r = 0; r < 4; r++)
            Lp[(long)jc * 2 * SEQL + grow0 + q * 4 + r] = lacc[r];
    }
    u16* Ob = Onum + ((long)jc * 2 * SEQL + grow0) * DP;
    #pragma unroll
    for (int n = 0; n < NQT; n++)
        #pragma unroll
        for (int r = 0; r < 4; r++)
            Ob[(long)(q * 4 + r) * DP + n * 16 + m] = f2bf(oacc[n][r]);
}

// ---------------- combine chunks + LayerNorm1: out = LN(sum(Onum)/sum(l) + XF) * g + b
__global__ __launch_bounds__(256) void lncomb_k(const u16* __restrict__ Onum, const float* __restrict__ Lp,
                                                const float* __restrict__ XF,
                                                const float* __restrict__ g, const float* __restrict__ b,
                                                u16* __restrict__ OutB)
{
    long row = (long)((blockIdx.x * blockDim.x + threadIdx.x) >> 6);
    int lane = threadIdx.x & 63;
    if (row >= 2L * SEQL) return;
    float l = 0.f;
    #pragma unroll
    for (int jc = 0; jc < JC; jc++) l += Lp[(long)jc * 2 * SEQL + row];
    float inv = 1.f / l;
    const float* xr = XF + row * DP;
    float v[5], sum = 0.f, sq = 0.f;
    #pragma unroll
    for (int i = 0; i < 5; i++){
        int c = lane + i * 64;
        float o = 0.f;
        #pragma unroll
        for (int jc = 0; jc < JC; jc++)
            o += bf2f(Onum[((long)jc * 2 * SEQL + row) * DP + c]);
        float t = (c < VECT) ? (o * inv + xr[c]) : 0.f;
        v[i] = t; sum += t; sq += t * t;
    }
    #pragma unroll
    for (int o = 1; o < 64; o <<= 1){ sum += __shfl_xor(sum, o); sq += __shfl_xor(sq, o); }
    float mean = sum / VECT;
    float var  = sq / VECT - mean * mean;
    float rstd = rsqrtf(var + 1e-5f);
    #pragma unroll
    for (int i = 0; i < 5; i++){
        int c = lane + i * 64;
        float t = (c < VECT) ? ((v[i] - mean) * rstd * g[c] + b[c]) : 0.f;
        OutB[row * DP + c] = f2bf(t);
    }
}

// ---------------- LayerNorm2: out = LN(Xf + Res) * g + b ; OutB bf16 + OutF fp32
__global__ __launch_bounds__(256) void ln_k(const float* __restrict__ Xf,
                                            const float* __restrict__ Res0, const float* __restrict__ Res1,
                                            int rstride,
                                            const float* __restrict__ g, const float* __restrict__ b,
                                            u16* __restrict__ OutB, float* __restrict__ OutF)
{
    long row = (long)((blockIdx.x * blockDim.x + threadIdx.x) >> 6);
    int lane = threadIdx.x & 63;
    if (row >= 2L * SEQL) return;
    const float* xr = Xf + row * DP;
    const float* rr = (row < SEQL) ? (Res0 + row * (long)rstride)
                                   : (Res1 + (row - SEQL) * (long)rstride);
    float v[5], sum = 0.f, sq = 0.f;
    #pragma unroll
    for (int i = 0; i < 5; i++){
        int c = lane + i * 64;
        float t = (c < VECT) ? (xr[c] + rr[c]) : 0.f;
        v[i] = t; sum += t; sq += t * t;
    }
    #pragma unroll
    for (int o = 1; o < 64; o <<= 1){ sum += __shfl_xor(sum, o); sq += __shfl_xor(sq, o); }
    float mean = sum / VECT;
    float var  = sq / VECT - mean * mean;
    float rstd = rsqrtf(var + 1e-5f);
    #pragma unroll
    for (int i = 0; i < 5; i++){
        int c = lane + i * 64;
        float t = (c < VECT) ? ((v[i] - mean) * rstd * g[c] + b[c]) : 0.f;
        OutB[row * DP + c] = f2bf(t);
        if (OutF) OutF[row * DP + c] = t;
    }
}

// ---------------- GRU: sequential scan, 1 WG per sequence, 4 waves, ONE raw barrier/step.
// fp8 K=128 scaled MFMA matvec (6 MFMAs/wave/step). gx staged via global_load_lds
// into triple-buffered LDS (t%3), issued at distance 2 by rotating waves (t&3==wid);
// the wave that issued 2 steps ago drains vmcnt before the step barrier -> no VGPR
// destinations, so the compiler cannot force an early vmcnt wait (r7's hidden stall).
__global__ __launch_bounds__(256, 1) void gru_k(
    const float* __restrict__ GX,                          // [2][SEQL][384] fp32
    const u8* __restrict__ Whh8,                           // [2][384][128] fp8 e4m3
    const float* __restrict__ Bhh1, const float* __restrict__ Bhh2,
    float* __restrict__ Hout)                              // [2][128] fp32
{
    const int s = blockIdx.x;
    const int lane = threadIdx.x & 63;
    const int wid  = threadIdx.x >> 6;
    const int m = lane & 15, q = lane >> 4;
    const u8* Whh = Whh8 + (long)s * G3 * HN;
    const float* Bhh = s ? Bhh2 : Bhh1;
    const float* gx = GX + (long)s * SEQL * G3;

    __shared__ __align__(16) float gxb[3][G3];      // triple-buffered gx staging (4.6 KB)
    __shared__ __align__(16) u8    hstage[4][HN];   // per-wave h in fp8 (128 B each)
    __shared__ __align__(16) float ghb[2][G3];      // double-buffered gh exchange

    // A-frags: 6 row-tiles x 32 k-bytes per lane (rows wid*96 + t6*16 + m, k = q*32..+31)
    v8i af[6];
    #pragma unroll
    for (int t6 = 0; t6 < 6; t6++)
        af[t6] = *(const v8i*)(Whh + (long)(wid * 96 + t6 * 16 + m) * HN + q * 32);

    const int i0 = 2 * lane, i1 = i0 + 1;
    const float bhr0 = Bhh[i0],        bhr1 = Bhh[i1];
    const float bhz0 = Bhh[HN + i0],   bhz1 = Bhh[HN + i1];
    const float bhn0 = Bhh[2*HN + i0], bhn1 = Bhh[2*HN + i1];

    // prologue: stage gx rows 0 and 1 into buffers 0,1 (wave 0)
    if (wid == 0){
        #pragma unroll
        for (int k = 0; k < 6; k++){
            __builtin_amdgcn_global_load_lds((const AS1 void*)(gx + k * 64 + lane),
                                             (AS3 void*)(&gxb[0][k * 64]), 4, 0, 0);
            __builtin_amdgcn_global_load_lds((const AS1 void*)(gx + G3 + k * 64 + lane),
                                             (AS3 void*)(&gxb[1][k * 64]), 4, 0, 0);
        }
    }
    asm volatile("s_waitcnt vmcnt(0)" ::: "memory");
    __syncthreads();

    float h0 = 0.f, h1 = 0.f;
    unsigned hpk = 0;                                // packed fp8 pair (h[i0],h[i1]) in low 16b
    const f32x4 zf = {0.f, 0.f, 0.f, 0.f};

    for (int t = 0; t < SEQL; t++){
        // 1. stage h_{t-1} (fp8 pair) into wave-private LDS; in-order within wave
        *(u16*)(&hstage[wid][lane * 2]) = (u16)hpk;
        // 2. B-frag: 32 fp8 h values at k = q*32..+31 (broadcast across m-lanes)
        v8i bfrag = *(const v8i*)(&hstage[wid][q * 32]);
        // 3. matvec: 6 independent K=128 scaled MFMAs
        #pragma unroll
        for (int t6 = 0; t6 < 6; t6++){
            f32x4 a = __builtin_amdgcn_mfma_scale_f32_16x16x128_f8f6f4(
                af[t6], bfrag, zf, 0, 0, 0, 127, 0, 127);
            if (m == 0)
                *(f32x4*)(&ghb[t & 1][wid * 96 + t6 * 16 + q * 4]) = a;
        }
        // 4. rotating gx staging: wave (t&3) issues loads for t+2 into buf[(t+2)%3]
        const int turn = t & 3;
        if (turn == wid && t + 2 < SEQL){
            const float* gs = gx + (long)(t + 2) * G3;
            float* lb = &gxb[(t + 2) % 3][0];
            #pragma unroll
            for (int k = 0; k < 6; k++)
                __builtin_amdgcn_global_load_lds((const AS1 void*)(gs + k * 64 + lane),
                                                 (AS3 void*)(lb + k * 64), 4, 0, 0);
        }
        // the wave that issued 2 steps ago drains its loads (long complete) pre-barrier
        if (((wid + 2) & 3) == turn)
            asm volatile("s_waitcnt vmcnt(0)" ::: "memory");
        // 5. raw barrier: publishes ghb(t), hstage, and gxb[(t+1)%3]
        asm volatile("s_waitcnt lgkmcnt(0)" ::: "memory");
        __builtin_amdgcn_s_barrier();
        asm volatile("" ::: "memory");
        // 6. gates (fp32); gx read from LDS (off the h critical path)
        const float* gb  = ghb[t & 1];
        const float* gxt = &gxb[t % 3][0];
        float2 cr  = *(const float2*)(gxt + i0);
        float2 cz  = *(const float2*)(gxt + HN + i0);
        float2 cn  = *(const float2*)(gxt + 2*HN + i0);
        float2 ghr = *(const float2*)(gb + i0);
        float2 ghz = *(const float2*)(gb + HN + i0);
        float2 ghn = *(const float2*)(gb + 2*HN + i0);

        float r0 = sigm_f(cr.x + ghr.x + bhr0);
        float r1 = sigm_f(cr.y + ghr.y + bhr1);
        float z0 = sigm_f(cz.x + ghz.x + bhz0);
        float z1 = sigm_f(cz.y + ghz.y + bhz1);
        float n0 = tanh_f(cn.x + r0 * (ghn.x + bhn0));
        float n1 = tanh_f(cn.y + r1 * (ghn.y + bhn1));
        h0 = (1.f - z0) * n0 + z0 * h0;
        h1 = (1.f - z1) * n1 + z1 * h1;
        hpk = (unsigned)__builtin_amdgcn_cvt_pk_fp8_f32(h0, h1, 0, false);
    }
    if (wid == 0){
        Hout[s * HN + i0] = h0;
        Hout[s * HN + i1] = h1;
    }
}

// ---------------- head: fc1+relu, fc2, log_softmax -> 3 fp32
__global__ __launch_bounds__(256) void final_k(const float* __restrict__ Hout,
                                               const float* __restrict__ fc1w, const float* __restrict__ fc1b,
                                               const float* __restrict__ fc2w, const float* __restrict__ fc2b,
                                               float* __restrict__ out)
{
    __shared__ float hb[256];
    __shared__ float r1[256];
    __shared__ float lg[3];
    int tid = threadIdx.x;
    hb[tid] = Hout[tid];
    __syncthreads();
    float a = 0.f;
    for (int k2 = 0; k2 < 256; k2++) a += hb[k2] * fc1w[tid * 256 + k2];
    a += fc1b[tid];
    r1[tid] = fmaxf(a, 0.f);
    __syncthreads();
    if (tid < 3){
        float v = 0.f;
        for (int k2 = 0; k2 < 256; k2++) v += r1[k2] * fc2w[tid * 256 + k2];
        lg[tid] = v + fc2b[tid];
    }
    __syncthreads();
    if (tid == 0){
        float mx = fmaxf(lg[0], fmaxf(lg[1], lg[2]));
        float se = __expf(lg[0] - mx) + __expf(lg[1] - mx) + __expf(lg[2] - mx);
        float ls = mx + logf(se);
        out[0] = lg[0] - ls;
        out[1] = lg[1] - ls;
        out[2] = lg[2] - ls;
    }
}

extern "C" void kernel_launch(void* const* d_in, const int* in_sizes, int n_in,
                              void* d_out, int out_size, void* d_ws, size_t ws_size,
                              hipStream_t stream)
{
    (void)in_sizes; (void)n_in; (void)out_size; (void)ws_size;
    const float* x1     = (const float*)d_in[0];
    const float* x2     = (const float*)d_in[1];
    const float* q_w    = (const float*)d_in[2],  *q_b   = (const float*)d_in[3];
    const float* k_w    = (const float*)d_in[4],  *k_b   = (const float*)d_in[5];
    const float* v_w    = (const float*)d_in[6],  *v_b   = (const float*)d_in[7];
    const float* aln_g  = (const float*)d_in[8],  *aln_b = (const float*)d_in[9];
    const float* w_w    = (const float*)d_in[10], *w_b   = (const float*)d_in[11];
    const float* mln_g  = (const float*)d_in[12], *mln_b = (const float*)d_in[13];
    const float* g1_wih = (const float*)d_in[14], *g1_whh = (const float*)d_in[15];
    const float* g1_bih = (const float*)d_in[16], *g1_bhh = (const float*)d_in[17];
    const float* g2_wih = (const float*)d_in[18], *g2_whh = (const float*)d_in[19];
    const float* g2_bih = (const float*)d_in[20], *g2_bhh = (const float*)d_in[21];
    const float* fc1w   = (const float*)d_in[22], *fc1b  = (const float*)d_in[23];
    const float* fc2w   = (const float*)d_in[24], *fc2b  = (const float*)d_in[25];

    char* wsp = (char*)d_ws;
    auto alloc = [&](size_t bytes) -> char* {
        char* p = wsp; wsp += (bytes + 255) & ~(size_t)255; return p;
    };
    float* XF   = (float*)alloc(2L * SEQL * DP * 4);   // fp32 stack input (residual for aln)
    u16*   CUR  = (u16*)  alloc(2L * SEQL * DP * 2);   // bf16 stack input (MFMA operand)
    u16*   Hb   = (u16*)  alloc(2L * SEQL * DP * 2);   // LN1 output bf16
    u16*   Wpk  = (u16*)  alloc(4L * DP * DP * 2);     // q,k,v,w packed bf16 [320][320]
    u16*   GWpk = (u16*)  alloc(2L * G3 * DP * 2);     // g{1,2}_wih packed bf16 [384][320]
    u8*    Whh8 = (u8*)   alloc(2L * G3 * HN);         // g{1,2}_whh fp8 [384][128]
    float* qbS  = (float*)alloc(DP * 4);               // q bias copy
    float* Hout = (float*)alloc(2L * HN * 4);
    float* Lp   = (float*)alloc((long)JC * 2 * SEQL * 4);
    // union1: {QK 2 slices + VT} vs GX
    size_t u1 = (2L * 2 * SEQL * DP + 2L * DP * SEQL) * 2;
    size_t u1b = 2L * SEQL * G3 * 4;
    u16*   QKV  = (u16*)  alloc(u1 > u1b ? u1 : u1b);
    u16*   VT   = QKV + 2L * 2 * SEQL * DP;
    float* GX   = (float*)QKV;
    // union2: Opart (flash numerator partials, bf16) vs Of (fp32 W-proj out)
    size_t u2 = (long)JC * 2 * SEQL * DP * 2;
    size_t u2b = 2L * SEQL * DP * 4;
    u16*   Onum = (u16*)  alloc(u2 > u2b ? u2 : u2b);
    float* Of   = (float*)Onum;

    // prep
    pad_x<<<256, 256, 0, stream>>>(x1, XF,                  CUR);
    pad_x<<<256, 256, 0, stream>>>(x2, XF + (long)SEQL*DP,  CUR + (long)SEQL*DP);
    cvt_pad<<<128, 256, 0, stream>>>(q_w, Wpk,                VECT, VECT, DP, DP, 1.f);
    cvt_pad<<<128, 256, 0, stream>>>(k_w, Wpk + 1L * DP * DP, VECT, VECT, DP, DP, 1.f);
    cvt_pad<<<128, 256, 0, stream>>>(v_w, Wpk + 2L * DP * DP, VECT, VECT, DP, DP, 1.f);
    cvt_pad<<<128, 256, 0, stream>>>(w_w, Wpk + 3L * DP * DP, VECT, VECT, DP, DP, 1.f);
    cvt_pad<<<128, 256, 0, stream>>>(g1_wih, GWpk,                 G3, VECT, G3, DP, 1.f);
    cvt_pad<<<128, 256, 0, stream>>>(g2_wih, GWpk + (long)G3 * DP, G3, VECT, G3, DP, 1.f);
    cvt_fp8<<<96, 256, 0, stream>>>(g1_whh, Whh8,                 G3 * HN);
    cvt_fp8<<<96, 256, 0, stream>>>(g2_whh, Whh8 + (long)G3 * HN, G3 * HN);
    scale_copy<<<2, 256, 0, stream>>>(q_b, qbS, VECT, 1.f);

    for (int st = 0; st < 3; ++st){
        // Q,K -> QKV slices 0,1 ; V -> transposed at slice 2 (VT)
        gemm_k<NQT, 3, false><<<dim3(SEQL / 64, 3, 2), 256, 0, stream>>>(
            CUR, Wpk, qbS, k_b, v_b, VECT, QKV);
        flash_k<<<dim3((SEQL / 64) * JC * 2), 256, 0, stream>>>(QKV, QKV + 2L*SEQL*DP, VT, Onum, Lp);
        lncomb_k<<<dim3(2 * SEQL / 4), 256, 0, stream>>>(Onum, Lp, XF, aln_g, aln_b, Hb);
        gemm_k<NQT, 1, false><<<dim3(SEQL / 64, 1, 2), 256, 0, stream>>>(
            Hb, Wpk + 3L * DP * DP, w_b, nullptr, nullptr, VECT, Of);
        ln_k<<<dim3(2 * SEQL / 4), 256, 0, stream>>>(Of, x1, x2, VECT, mln_g, mln_b, CUR, XF);
    }

    // GRU input projections (weight/bias per seq) -> GX (aliases QKV, now dead)
    gemm_k<24, 1, true><<<dim3(SEQL / 64, 1, 2), 256, 0, stream>>>(
        CUR, GWpk, g1_bih, g2_bih, nullptr, G3, GX);
    gru_k<<<dim3(2), 256, 0, stream>>>(GX, Whh8, g1_bhh, g2_bhh, Hout);
    final_k<<<dim3(1), 256, 0, stream>>>(Hout, fc1w, fc1b, fc2w, fc2b, (float*)d_out);
}

// Round 9
// 3111.710 us; speedup vs baseline: 1.3537x; 1.3537x over previous
//
#include <hip/hip_runtime.h>
#include <hip/hip_bf16.h>

// Problem constants
#define SEQL 4096
#define VECT 300
#define DP   320     // padded feature dim (k-dim), 10 chunks of 32
#define NQT  20      // n-tiles (320 cols) for projection GEMMs
#define HN   128
#define G3   384     // 3*H
#define JC   4       // flash j-chunks (split-K over key dim)
#define KROW 328     // LDS K-tile row stride (u16): 656B, 16B-aligned, 2-way banks
#define VROW 40      // LDS VT-tile row stride (u16): 80B, 16B-aligned, 2-way banks
#define PROW 40      // pbuf row stride

typedef unsigned short u16;
typedef unsigned char  u8;
typedef __attribute__((ext_vector_type(8))) short bf16x8;  // 8 bf16 = 4 VGPRs
typedef __attribute__((ext_vector_type(4))) float f32x4;
typedef __attribute__((ext_vector_type(4))) unsigned int u32x4;

#define MFMA(a,b,c) __builtin_amdgcn_mfma_f32_16x16x32_bf16(a,b,c,0,0,0)
// Verified layouts (learn_hip m89/m91/m120):
//   A[m][k]: m=lane&15, k=(lane>>4)*8+j
//   B[k][n]: n=lane&15, k=(lane>>4)*8+j
//   C/D[row][col]: col=lane&15, row=(lane>>4)*4+reg

#define L2E 1.44269504088896f

__device__ __forceinline__ float bf2f(u16 v){
    union { unsigned u; float f; } t; t.u = ((unsigned)v) << 16; return t.f;
}
__device__ __forceinline__ u16 f2bf(float f){
    union { float f; unsigned u; } t; t.f = f;
    return (u16)((t.u + 0x7FFFu + ((t.u >> 16) & 1u)) >> 16);
}
__device__ __forceinline__ float sigm_f(float x){
    return __builtin_amdgcn_rcpf(1.f + __builtin_amdgcn_exp2f(-L2E * x));
}
__device__ __forceinline__ float tanh_f(float x){
    return fmaf(2.f, __builtin_amdgcn_rcpf(1.f + __builtin_amdgcn_exp2f(-2.f * L2E * x)), -1.f);
}

// ---------------- fp32 [R][C] -> bf16 padded [Rp][Cp], optional scale
__global__ __launch_bounds__(256) void cvt_pad(const float* __restrict__ src,
                                               u16* __restrict__ dst,
                                               int R, int C, int Rp, int Cp, float scale)
{
    int n = Rp * Cp;
    for (int i = blockIdx.x * blockDim.x + threadIdx.x; i < n; i += gridDim.x * blockDim.x){
        int r = i / Cp, c = i - r * Cp;
        float v = (r < R && c < C) ? src[r * C + c] * scale : 0.f;
        dst[i] = f2bf(v);
    }
}

// ---------------- fp32 vector scale-copy
__global__ __launch_bounds__(256) void scale_copy(const float* __restrict__ src,
                                                  float* __restrict__ dst, int n, float scale)
{
    int i = blockIdx.x * blockDim.x + threadIdx.x;
    if (i < n) dst[i] = src[i] * scale;
}

// ---------------- x: fp32 [S][300] -> XF fp32 [S][320] + CUR bf16 [S][320]
__global__ __launch_bounds__(256) void pad_x(const float* __restrict__ src,
                                             float* __restrict__ xf, u16* __restrict__ cur)
{
    int n = SEQL * DP;
    for (int i = blockIdx.x * blockDim.x + threadIdx.x; i < n; i += gridDim.x * blockDim.x){
        int r = i / DP, c = i - r * DP;
        float v = (c < VECT) ? src[r * VECT + c] : 0.f;
        xf[i]  = v;
        cur[i] = f2bf(v);
    }
}

// ---------------- GEMM: Y[s][i][col] = sum_d A[s][i][d] * W[wsel][col][d] + bias[col]
// 256 thr = 4 waves; wave handles 16 rows; WG = 64 rows.
// OM: 1 = fp32 row-major; 3 = QKV fused: slices 0,1 bf16 row-major, slice 2 bf16 transposed.
template<int NT, int OM, bool WPERSEQ>
__global__ __launch_bounds__(256) void gemm_k(
    const u16* __restrict__ A, const u16* __restrict__ Wp,
    const float* __restrict__ b0, const float* __restrict__ b1, const float* __restrict__ b2,
    int nb, void* __restrict__ Out)
{
    const int lane = threadIdx.x & 63;
    const int wid  = threadIdx.x >> 6;
    const int s    = blockIdx.z;
    const int sl   = blockIdx.y;
    const int wsel = WPERSEQ ? s : sl;
    const int row0 = blockIdx.x * 64 + wid * 16;
    const int m    = lane & 15;
    const int q    = lane >> 4;

    const u16* Arow = A + ((long)s * SEQL + row0) * DP;
    const u16* W    = Wp + (long)wsel * (NT * 16) * DP;

    f32x4 zf = {0.f, 0.f, 0.f, 0.f};
    f32x4 acc[NT];
    #pragma unroll
    for (int n = 0; n < NT; n++) acc[n] = zf;

    for (int c = 0; c < DP / 32; ++c){
        const int koff = c * 32 + q * 8;
        bf16x8 a0 = *(const bf16x8*)(Arow + m * DP + koff);
        #pragma unroll
        for (int n = 0; n < NT; n++){
            bf16x8 b = *(const bf16x8*)(W + (n * 16 + m) * DP + koff);
            acc[n] = MFMA(a0, b, acc[n]);
        }
    }

    const int bsel = WPERSEQ ? s : sl;
    const float* bp = (bsel == 0) ? b0 : ((bsel == 1) ? b1 : b2);
    const long SLC = 2L * SEQL * DP;  // per-slice stride in QKV buffer

    #pragma unroll
    for (int n = 0; n < NT; n++){
        int col = n * 16 + m;
        float bv = (col < nb) ? bp[col] : 0.f;
        #pragma unroll
        for (int r = 0; r < 4; r++){
            long row = row0 + q * 4 + r;
            float v = acc[n][r] + bv;
            if (OM == 1){
                long off = ((long)s * SEQL + row) * (long)(NT * 16) + col;
                ((float*)Out)[off] = v;
            } else {  // OM == 3
                long off;
                if (sl < 2) off = ((long)(sl * 2 + s) * SEQL + row) * DP + col;
                else        off = 2 * SLC + ((long)s * DP + col) * SEQL + row;
                ((u16*)Out)[off] = f2bf(v);
            }
        }
    }
}

// ---------------- flash attention chunk, LDS-tiled:
// WG covers 128 Q-rows (wave = 32 rows, 2 m-tiles); per j (32 keys) the K-tile (32x320)
// and VT-tile (320x32) are staged ONCE into LDS (bank-safe padded strides) and shared by
// all 4 waves: per-WG traffic 40KB/j instead of 160KB/j -> L2/HBM pressure drops 4x+.
// Staging is register-roundtrip (padded LDS layouts break global_load_lds lane mapping),
// preloaded to VGPRs before compute(j) so the global latency overlaps the 80 MFMAs.
// Grid 256 linear = 32 xi * 8 combos; combo=bid&7 -> (jc,s) for XCD L2 locality.
__global__ __launch_bounds__(256, 1) void flash_k(
    const u16* __restrict__ Q, const u16* __restrict__ K, const u16* __restrict__ VT,
    u16* __restrict__ Onum, float* __restrict__ Lp)
{
    const int tid  = threadIdx.x;
    const int lane = tid & 63;
    const int wid  = tid >> 6;
    const int bid  = blockIdx.x;
    const int s    = bid & 1;
    const int jc   = (bid >> 1) & 3;
    const int xi   = bid >> 3;
    const int row0 = xi * 128 + wid * 32;
    const int m = lane & 15, q = lane >> 4;

    __shared__ __align__(16) u16 Kt[32 * KROW];        // 21.0 KB
    __shared__ __align__(16) u16 Vt[DP * VROW];        // 25.6 KB
    __shared__ __align__(16) u16 pb[4][2][16 * PROW];  // 10.2 KB

    const u16* Qb = Q  + ((long)s * SEQL + row0) * DP;
    const u16* Kc = K  + (long)s * SEQL * DP + (long)jc * 1024 * DP;  // chunk: 1024 keys
    const u16* Vc = VT + (long)s * DP * SEQL + jc * 1024;

    // Q fragments: 2 m-tiles x 10 k-chunks
    bf16x8 qf0[10], qf1[10];
    #pragma unroll
    for (int c = 0; c < 10; c++){
        qf0[c] = *(const bf16x8*)(Qb + (m     ) * DP + c * 32 + q * 8);
        qf1[c] = *(const bf16x8*)(Qb + (m + 16) * DP + c * 32 + q * 8);
    }

    // staging address precompute (j-independent)
    int skoff[5], wkoff[5], svoff[5], wvoff[5];
    #pragma unroll
    for (int it = 0; it < 5; it++){
        int f  = (it * 256 + tid) * 8;      // flat u16 index into 32x320 tile
        int rk = f / 320, ck = f - rk * 320;
        skoff[it] = f;                      // K source is contiguous [32][320]
        wkoff[it] = rk * KROW + ck;
        int rv = f >> 5, cv = f & 31;       // VT tile as [320][32]
        svoff[it] = rv * SEQL + cv;
        wvoff[it] = rv * VROW + cv;
    }

    f32x4 zf = {0.f, 0.f, 0.f, 0.f};
    f32x4 oacc0[NQT], oacc1[NQT];
    #pragma unroll
    for (int n = 0; n < NQT; n++){ oacc0[n] = zf; oacc1[n] = zf; }
    float lacc0[4] = {0,0,0,0}, lacc1[4] = {0,0,0,0};

    const float K2 = 0.057735026918962576f * L2E;  // (1/sqrt(300)) * log2(e)
    const float MB = -16.f * L2E;                   // fixed max offset (scores bounded ~|4|)

    u32x4 kreg[5], vreg[5];
    // stage j = 0
    #pragma unroll
    for (int it = 0; it < 5; it++){
        kreg[it] = *(const u32x4*)(Kc + skoff[it]);
        vreg[it] = *(const u32x4*)(Vc + svoff[it]);
    }
    #pragma unroll
    for (int it = 0; it < 5; it++){
        *(u32x4*)(&Kt[wkoff[it]]) = kreg[it];
        *(u32x4*)(&Vt[wvoff[it]]) = vreg[it];
    }
    __syncthreads();

    u16* pb0 = &pb[wid][0][0];
    u16* pb1 = &pb[wid][1][0];

    for (int j = 0; j < 32; ++j){
        // preload j+1 tiles into registers (in flight during compute)
        if (j + 1 < 32){
            const u16* Kj = Kc + (j + 1) * 32 * DP;
            const u16* Vj = Vc + (j + 1) * 32;
            #pragma unroll
            for (int it = 0; it < 5; it++){
                kreg[it] = *(const u32x4*)(Kj + skoff[it]);
                vreg[it] = *(const u32x4*)(Vj + svoff[it]);
            }
        }
        // QK^T: 40 MFMAs (2 m-tiles x 10 c x 2 key-halves)
        f32x4 s0A = zf, s0B = zf, s1A = zf, s1B = zf;
        #pragma unroll
        for (int c = 0; c < 10; c++){
            bf16x8 kA = *(const bf16x8*)(&Kt[(m     ) * KROW + c * 32 + q * 8]);
            bf16x8 kB = *(const bf16x8*)(&Kt[(m + 16) * KROW + c * 32 + q * 8]);
            s0A = MFMA(qf0[c], kA, s0A);
            s0B = MFMA(qf0[c], kB, s0B);
            s1A = MFMA(qf1[c], kA, s1A);
            s1B = MFMA(qf1[c], kB, s1B);
        }
        // exp + P -> LDS (C-layout -> A-layout roundtrip)
        #pragma unroll
        for (int r = 0; r < 4; r++){
            float a0 = __builtin_amdgcn_exp2f(fmaf(s0A[r], K2, MB));
            float b0 = __builtin_amdgcn_exp2f(fmaf(s0B[r], K2, MB));
            float a1 = __builtin_amdgcn_exp2f(fmaf(s1A[r], K2, MB));
            float b1 = __builtin_amdgcn_exp2f(fmaf(s1B[r], K2, MB));
            lacc0[r] += a0 + b0;
            lacc1[r] += a1 + b1;
            pb0[(q * 4 + r) * PROW +      m] = f2bf(a0);
            pb0[(q * 4 + r) * PROW + 16 + m] = f2bf(b0);
            pb1[(q * 4 + r) * PROW +      m] = f2bf(a1);
            pb1[(q * 4 + r) * PROW + 16 + m] = f2bf(b1);
        }
        bf16x8 pf0 = *(const bf16x8*)(&pb0[m * PROW + q * 8]);
        bf16x8 pf1 = *(const bf16x8*)(&pb1[m * PROW + q * 8]);
        // PV: 40 MFMAs (2 m-tiles x 20 n-tiles)
        #pragma unroll
        for (int n = 0; n < NQT; n++){
            bf16x8 vb = *(const bf16x8*)(&Vt[(n * 16 + m) * VROW + q * 8]);
            oacc0[n] = MFMA(pf0, vb, oacc0[n]);
            oacc1[n] = MFMA(pf1, vb, oacc1[n]);
        }
        __syncthreads();              // all waves done reading Kt/Vt for j
        if (j + 1 < 32){
            #pragma unroll
            for (int it = 0; it < 5; it++){
                *(u32x4*)(&Kt[wkoff[it]]) = kreg[it];
                *(u32x4*)(&Vt[wvoff[it]]) = vreg[it];
            }
        }
        __syncthreads();              // tiles for j+1 published
    }

    // reduce l over the 16 m-lanes (columns)
    #pragma unroll
    for (int r = 0; r < 4; r++){
        float t0 = lacc0[r], t1 = lacc1[r];
        t0 += __shfl_xor(t0, 1); t0 += __shfl_xor(t0, 2);
        t0 += __shfl_xor(t0, 4); t0 += __shfl_xor(t0, 8);
        t1 += __shfl_xor(t1, 1); t1 += __shfl_xor(t1, 2);
        t1 += __shfl_xor(t1, 4); t1 += __shfl_xor(t1, 8);
        lacc0[r] = t0; lacc1[r] = t1;
    }
    const long grow0 = (long)s * SEQL + row0;
    if (m == 0){
        #pragma unroll
        for (int r = 0; r < 4; r++){
            Lp[(long)jc * 2 * SEQL + grow0 +      q * 4 + r] = lacc0[r];
            Lp[(long)jc * 2 * SEQL + grow0 + 16 + q * 4 + r] = lacc1[r];
        }
    }
    u16* Ob = Onum + ((long)jc * 2 * SEQL + grow0) * DP;
    #pragma unroll
    for (int n = 0; n < NQT; n++)
        #pragma unroll
        for (int r = 0; r < 4; r++){
            Ob[(long)(     q * 4 + r) * DP + n * 16 + m] = f2bf(oacc0[n][r]);
            Ob[(long)(16 + q * 4 + r) * DP + n * 16 + m] = f2bf(oacc1[n][r]);
        }
}

// ---------------- combine chunks + LayerNorm1: out = LN(sum(Onum)/sum(l) + XF) * g + b
__global__ __launch_bounds__(256) void lncomb_k(const u16* __restrict__ Onum, const float* __restrict__ Lp,
                                                const float* __restrict__ XF,
                                                const float* __restrict__ g, const float* __restrict__ b,
                                                u16* __restrict__ OutB)
{
    long row = (long)((blockIdx.x * blockDim.x + threadIdx.x) >> 6);
    int lane = threadIdx.x & 63;
    if (row >= 2L * SEQL) return;
    float l = 0.f;
    #pragma unroll
    for (int jc = 0; jc < JC; jc++) l += Lp[(long)jc * 2 * SEQL + row];
    float inv = 1.f / l;
    const float* xr = XF + row * DP;
    float v[5], sum = 0.f, sq = 0.f;
    #pragma unroll
    for (int i = 0; i < 5; i++){
        int c = lane + i * 64;
        float o = 0.f;
        #pragma unroll
        for (int jc = 0; jc < JC; jc++)
            o += bf2f(Onum[((long)jc * 2 * SEQL + row) * DP + c]);
        float t = (c < VECT) ? (o * inv + xr[c]) : 0.f;
        v[i] = t; sum += t; sq += t * t;
    }
    #pragma unroll
    for (int o = 1; o < 64; o <<= 1){ sum += __shfl_xor(sum, o); sq += __shfl_xor(sq, o); }
    float mean = sum / VECT;
    float var  = sq / VECT - mean * mean;
    float rstd = rsqrtf(var + 1e-5f);
    #pragma unroll
    for (int i = 0; i < 5; i++){
        int c = lane + i * 64;
        float t = (c < VECT) ? ((v[i] - mean) * rstd * g[c] + b[c]) : 0.f;
        OutB[row * DP + c] = f2bf(t);
    }
}

// ---------------- LayerNorm2: out = LN(Xf + Res) * g + b ; OutB bf16 + OutF fp32
__global__ __launch_bounds__(256) void ln_k(const float* __restrict__ Xf,
                                            const float* __restrict__ Res0, const float* __restrict__ Res1,
                                            int rstride,
                                            const float* __restrict__ g, const float* __restrict__ b,
                                            u16* __restrict__ OutB, float* __restrict__ OutF)
{
    long row = (long)((blockIdx.x * blockDim.x + threadIdx.x) >> 6);
    int lane = threadIdx.x & 63;
    if (row >= 2L * SEQL) return;
    const float* xr = Xf + row * DP;
    const float* rr = (row < SEQL) ? (Res0 + row * (long)rstride)
                                   : (Res1 + (row - SEQL) * (long)rstride);
    float v[5], sum = 0.f, sq = 0.f;
    #pragma unroll
    for (int i = 0; i < 5; i++){
        int c = lane + i * 64;
        float t = (c < VECT) ? (xr[c] + rr[c]) : 0.f;
        v[i] = t; sum += t; sq += t * t;
    }
    #pragma unroll
    for (int o = 1; o < 64; o <<= 1){ sum += __shfl_xor(sum, o); sq += __shfl_xor(sq, o); }
    float mean = sum / VECT;
    float var  = sq / VECT - mean * mean;
    float rstd = rsqrtf(var + 1e-5f);
    #pragma unroll
    for (int i = 0; i < 5; i++){
        int c = lane + i * 64;
        float t = (c < VECT) ? ((v[i] - mean) * rstd * g[c] + b[c]) : 0.f;
        OutB[row * DP + c] = f2bf(t);
        if (OutF) OutF[row * DP + c] = t;
    }
}

// ---------------- GRU (r6 config — best measured): 1 WG per sequence, 4 waves, ONE raw
// barrier/step, wave-private LDS h staging, bf16 MFMA, gx register prefetch distance 1.
__global__ __launch_bounds__(256, 1) void gru_k(
    const float* __restrict__ GX,                          // [2][SEQL][384] fp32
    const u16* __restrict__ WhhB,                          // [2][384][128] bf16
    const float* __restrict__ Bhh1, const float* __restrict__ Bhh2,
    float* __restrict__ Hout)                              // [2][128] fp32
{
    const int s = blockIdx.x;
    const int lane = threadIdx.x & 63;
    const int wid  = threadIdx.x >> 6;
    const int m = lane & 15, q = lane >> 4;
    const u16* Whh = WhhB + (long)s * G3 * HN;
    const float* Bhh = s ? Bhh2 : Bhh1;
    const float* gx = GX + (long)s * SEQL * G3;

    __shared__ __align__(16) u16   hstage[4][HN];   // per-wave private h copy (256 B each)
    __shared__ __align__(16) float ghb[2][G3];      // double-buffered gh exchange

    bf16x8 af[6][4];
    #pragma unroll
    for (int t6 = 0; t6 < 6; t6++)
        #pragma unroll
        for (int c = 0; c < 4; c++)
            af[t6][c] = *(const bf16x8*)(Whh + (wid * 96 + t6 * 16 + m) * HN + c * 32 + q * 8);

    const int i0 = 2 * lane, i1 = i0 + 1;
    const float bhr0 = Bhh[i0],        bhr1 = Bhh[i1];
    const float bhz0 = Bhh[HN + i0],   bhz1 = Bhh[HN + i1];
    const float bhn0 = Bhh[2*HN + i0], bhn1 = Bhh[2*HN + i1];

    float2 cr = *(const float2*)(gx + i0);
    float2 cz = *(const float2*)(gx + HN + i0);
    float2 cn = *(const float2*)(gx + 2*HN + i0);

    float h0 = 0.f, h1 = 0.f;
    unsigned hpk = 0;
    const f32x4 zf = {0.f, 0.f, 0.f, 0.f};
    unsigned* hsw = (unsigned*)&hstage[wid][0];

    for (int t = 0; t < SEQL; t++){
        hsw[lane] = hpk;
        int tn = (t + 1 < SEQL) ? t + 1 : t;
        const float* gp = gx + (long)tn * G3;
        float2 pr = *(const float2*)(gp + i0);
        float2 pz = *(const float2*)(gp + HN + i0);
        float2 pn = *(const float2*)(gp + 2*HN + i0);
        bf16x8 bf_[4];
        #pragma unroll
        for (int c = 0; c < 4; c++)
            bf_[c] = *(const bf16x8*)(&hstage[wid][c * 32 + q * 8]);
        #pragma unroll
        for (int t6 = 0; t6 < 6; t6++){
            f32x4 a = zf;
            #pragma unroll
            for (int c = 0; c < 4; c++) a = MFMA(af[t6][c], bf_[c], a);
            if (m == 0)
                *(f32x4*)(&ghb[t & 1][wid * 96 + t6 * 16 + q * 4]) = a;
        }
        asm volatile("s_waitcnt lgkmcnt(0)" ::: "memory");
        __builtin_amdgcn_s_barrier();
        asm volatile("" ::: "memory");
        const float* gb = ghb[t & 1];
        float2 ghr = *(const float2*)(gb + i0);
        float2 ghz = *(const float2*)(gb + HN + i0);
        float2 ghn = *(const float2*)(gb + 2*HN + i0);

        float r0 = sigm_f(cr.x + ghr.x + bhr0);
        float r1 = sigm_f(cr.y + ghr.y + bhr1);
        float z0 = sigm_f(cz.x + ghz.x + bhz0);
        float z1 = sigm_f(cz.y + ghz.y + bhz1);
        float n0 = tanh_f(cn.x + r0 * (ghn.x + bhn0));
        float n1 = tanh_f(cn.y + r1 * (ghn.y + bhn1));
        h0 = (1.f - z0) * n0 + z0 * h0;
        h1 = (1.f - z1) * n1 + z1 * h1;
        hpk = ((unsigned)f2bf(h1) << 16) | (unsigned)f2bf(h0);
        cr = pr; cz = pz; cn = pn;
    }
    if (wid == 0){
        Hout[s * HN + i0] = h0;
        Hout[s * HN + i1] = h1;
    }
}

// ---------------- head: fc1+relu, fc2, log_softmax -> 3 fp32
__global__ __launch_bounds__(256) void final_k(const float* __restrict__ Hout,
                                               const float* __restrict__ fc1w, const float* __restrict__ fc1b,
                                               const float* __restrict__ fc2w, const float* __restrict__ fc2b,
                                               float* __restrict__ out)
{
    __shared__ float hb[256];
    __shared__ float r1[256];
    __shared__ float lg[3];
    int tid = threadIdx.x;
    hb[tid] = Hout[tid];
    __syncthreads();
    float a = 0.f;
    for (int k2 = 0; k2 < 256; k2++) a += hb[k2] * fc1w[tid * 256 + k2];
    a += fc1b[tid];
    r1[tid] = fmaxf(a, 0.f);
    __syncthreads();
    if (tid < 3){
        float v = 0.f;
        for (int k2 = 0; k2 < 256; k2++) v += r1[k2] * fc2w[tid * 256 + k2];
        lg[tid] = v + fc2b[tid];
    }
    __syncthreads();
    if (tid == 0){
        float mx = fmaxf(lg[0], fmaxf(lg[1], lg[2]));
        float se = __expf(lg[0] - mx) + __expf(lg[1] - mx) + __expf(lg[2] - mx);
        float ls = mx + logf(se);
        out[0] = lg[0] - ls;
        out[1] = lg[1] - ls;
        out[2] = lg[2] - ls;
    }
}

extern "C" void kernel_launch(void* const* d_in, const int* in_sizes, int n_in,
                              void* d_out, int out_size, void* d_ws, size_t ws_size,
                              hipStream_t stream)
{
    (void)in_sizes; (void)n_in; (void)out_size; (void)ws_size;
    const float* x1     = (const float*)d_in[0];
    const float* x2     = (const float*)d_in[1];
    const float* q_w    = (const float*)d_in[2],  *q_b   = (const float*)d_in[3];
    const float* k_w    = (const float*)d_in[4],  *k_b   = (const float*)d_in[5];
    const float* v_w    = (const float*)d_in[6],  *v_b   = (const float*)d_in[7];
    const float* aln_g  = (const float*)d_in[8],  *aln_b = (const float*)d_in[9];
    const float* w_w    = (const float*)d_in[10], *w_b   = (const float*)d_in[11];
    const float* mln_g  = (const float*)d_in[12], *mln_b = (const float*)d_in[13];
    const float* g1_wih = (const float*)d_in[14], *g1_whh = (const float*)d_in[15];
    const float* g1_bih = (const float*)d_in[16], *g1_bhh = (const float*)d_in[17];
    const float* g2_wih = (const float*)d_in[18], *g2_whh = (const float*)d_in[19];
    const float* g2_bih = (const float*)d_in[20], *g2_bhh = (const float*)d_in[21];
    const float* fc1w   = (const float*)d_in[22], *fc1b  = (const float*)d_in[23];
    const float* fc2w   = (const float*)d_in[24], *fc2b  = (const float*)d_in[25];

    char* wsp = (char*)d_ws;
    auto alloc = [&](size_t bytes) -> char* {
        char* p = wsp; wsp += (bytes + 255) & ~(size_t)255; return p;
    };
    float* XF   = (float*)alloc(2L * SEQL * DP * 4);   // fp32 stack input (residual for aln)
    u16*   CUR  = (u16*)  alloc(2L * SEQL * DP * 2);   // bf16 stack input (MFMA operand)
    u16*   Hb   = (u16*)  alloc(2L * SEQL * DP * 2);   // LN1 output bf16
    u16*   Wpk  = (u16*)  alloc(4L * DP * DP * 2);     // q,k,v,w packed bf16 [320][320]
    u16*   GWpk = (u16*)  alloc(2L * G3 * DP * 2);     // g{1,2}_wih packed bf16 [384][320]
    u16*   WhhB = (u16*)  alloc(2L * G3 * HN * 2);     // g{1,2}_whh bf16 [384][128]
    float* qbS  = (float*)alloc(DP * 4);               // q bias copy
    float* Hout = (float*)alloc(2L * HN * 4);
    float* Lp   = (float*)alloc((long)JC * 2 * SEQL * 4);
    // union1: {QK 2 slices + VT} vs GX
    size_t u1 = (2L * 2 * SEQL * DP + 2L * DP * SEQL) * 2;
    size_t u1b = 2L * SEQL * G3 * 4;
    u16*   QKV  = (u16*)  alloc(u1 > u1b ? u1 : u1b);
    u16*   VT   = QKV + 2L * 2 * SEQL * DP;
    float* GX   = (float*)QKV;
    // union2: Opart (flash numerator partials, bf16) vs Of (fp32 W-proj out)
    size_t u2 = (long)JC * 2 * SEQL * DP * 2;
    size_t u2b = 2L * SEQL * DP * 4;
    u16*   Onum = (u16*)  alloc(u2 > u2b ? u2 : u2b);
    float* Of   = (float*)Onum;

    // prep
    pad_x<<<256, 256, 0, stream>>>(x1, XF,                  CUR);
    pad_x<<<256, 256, 0, stream>>>(x2, XF + (long)SEQL*DP,  CUR + (long)SEQL*DP);
    cvt_pad<<<128, 256, 0, stream>>>(q_w, Wpk,                VECT, VECT, DP, DP, 1.f);
    cvt_pad<<<128, 256, 0, stream>>>(k_w, Wpk + 1L * DP * DP, VECT, VECT, DP, DP, 1.f);
    cvt_pad<<<128, 256, 0, stream>>>(v_w, Wpk + 2L * DP * DP, VECT, VECT, DP, DP, 1.f);
    cvt_pad<<<128, 256, 0, stream>>>(w_w, Wpk + 3L * DP * DP, VECT, VECT, DP, DP, 1.f);
    cvt_pad<<<128, 256, 0, stream>>>(g1_wih, GWpk,                 G3, VECT, G3, DP, 1.f);
    cvt_pad<<<128, 256, 0, stream>>>(g2_wih, GWpk + (long)G3 * DP, G3, VECT, G3, DP, 1.f);
    cvt_pad<<<64, 256, 0, stream>>>(g1_whh, WhhB,                 G3, HN, G3, HN, 1.f);
    cvt_pad<<<64, 256, 0, stream>>>(g2_whh, WhhB + (long)G3 * HN, G3, HN, G3, HN, 1.f);
    scale_copy<<<2, 256, 0, stream>>>(q_b, qbS, VECT, 1.f);

    for (int st = 0; st < 3; ++st){
        // Q,K -> QKV slices 0,1 ; V -> transposed at slice 2 (VT)
        gemm_k<NQT, 3, false><<<dim3(SEQL / 64, 3, 2), 256, 0, stream>>>(
            CUR, Wpk, qbS, k_b, v_b, VECT, QKV);
        flash_k<<<dim3(256), 256, 0, stream>>>(QKV, QKV + 2L*SEQL*DP, VT, Onum, Lp);
        lncomb_k<<<dim3(2 * SEQL / 4), 256, 0, stream>>>(Onum, Lp, XF, aln_g, aln_b, Hb);
        gemm_k<NQT, 1, false><<<dim3(SEQL / 64, 1, 2), 256, 0, stream>>>(
            Hb, Wpk + 3L * DP * DP, w_b, nullptr, nullptr, VECT, Of);
        ln_k<<<dim3(2 * SEQL / 4), 256, 0, stream>>>(Of, x1, x2, VECT, mln_g, mln_b, CUR, XF);
    }

    // GRU input projections (weight/bias per seq) -> GX (aliases QKV, now dead)
    gemm_k<24, 1, true><<<dim3(SEQL / 64, 1, 2), 256, 0, stream>>>(
        CUR, GWpk, g1_bih, g2_bih, nullptr, G3, GX);
    gru_k<<<dim3(2), 256, 0, stream>>>(GX, WhhB, g1_bhh, g2_bhh, Hout);
    final_k<<<dim3(1), 256, 0, stream>>>(Hout, fc1w, fc1b, fc2w, fc2b, (float*)d_out);
}

// Round 10
// 2100.543 us; speedup vs baseline: 2.0054x; 1.4814x over previous
//
#include <hip/hip_runtime.h>
#include <hip/hip_bf16.h>

// Problem constants
#define SEQL 4096
#define VECT 300
#define DP   320     // padded feature dim (k-dim), 10 chunks of 32
#define NQT  20      // n-tiles (320 cols) for projection GEMMs
#define HN   128
#define G3   384     // 3*H
#define JC   4       // flash j-chunks (split-K over key dim)
#define KROW 328     // LDS K-tile row stride (u16)
#define VROW 40      // LDS VT-tile row stride (u16)
#define PROW 40      // pbuf row stride

typedef unsigned short u16;
typedef unsigned char  u8;
typedef __attribute__((ext_vector_type(8))) short bf16x8;  // 8 bf16 = 4 VGPRs
typedef __attribute__((ext_vector_type(4))) float f32x4;
typedef __attribute__((ext_vector_type(4))) unsigned int u32x4;
typedef __attribute__((ext_vector_type(8))) int   v8i;     // 8 dwords (fp8 x32)

#define MFMA(a,b,c) __builtin_amdgcn_mfma_f32_16x16x32_bf16(a,b,c,0,0,0)
// Verified layouts (learn_hip m89/m91/m120):
//   A[m][k]: m=lane&15, k=(lane>>4)*8+j
//   B[k][n]: n=lane&15, k=(lane>>4)*8+j
//   C/D[row][col]: col=lane&15, row=(lane>>4)*4+reg

#define L2E 1.44269504088896f

__device__ __forceinline__ float bf2f(u16 v){
    union { unsigned u; float f; } t; t.u = ((unsigned)v) << 16; return t.f;
}
__device__ __forceinline__ u16 f2bf(float f){
    union { float f; unsigned u; } t; t.f = f;
    return (u16)((t.u + 0x7FFFu + ((t.u >> 16) & 1u)) >> 16);
}
__device__ __forceinline__ float sigm_f(float x){
    return __builtin_amdgcn_rcpf(1.f + __builtin_amdgcn_exp2f(-L2E * x));
}
__device__ __forceinline__ float tanh_f(float x){
    return fmaf(2.f, __builtin_amdgcn_rcpf(1.f + __builtin_amdgcn_exp2f(-2.f * L2E * x)), -1.f);
}
__device__ __forceinline__ float sel4(f32x4 v, int r){
    float a = (r & 1) ? v.y : v.x;
    float b = (r & 1) ? v.w : v.z;
    return (r & 2) ? b : a;
}

// ---------------- fp32 [R][C] -> bf16 padded [Rp][Cp], optional scale
__global__ __launch_bounds__(256) void cvt_pad(const float* __restrict__ src,
                                               u16* __restrict__ dst,
                                               int R, int C, int Rp, int Cp, float scale)
{
    int n = Rp * Cp;
    for (int i = blockIdx.x * blockDim.x + threadIdx.x; i < n; i += gridDim.x * blockDim.x){
        int r = i / Cp, c = i - r * Cp;
        float v = (r < R && c < C) ? src[r * C + c] * scale : 0.f;
        dst[i] = f2bf(v);
    }
}

// ---------------- Whh: fp32 [384][128] (row = g*128+i) -> fp8, permuted rows:
// prow = w*96 + tg*48 + g*16 + rr  <->  orig row g*128 + (w*32 + tg*16 + rr)
// so each wave's 6 MFMA tiles are (tg,g) blocks of ITS OWN 32 h-indices.
__global__ __launch_bounds__(256) void cvt_whh(const float* __restrict__ src,
                                               u8* __restrict__ dst)
{
    int idx = blockIdx.x * 256 + threadIdx.x;
    if (idx >= G3 * HN) return;
    int prow = idx >> 7, col = idx & 127;
    int w  = prow / 96, rem = prow - w * 96;
    int tg = rem / 48;  rem -= tg * 48;
    int g  = rem >> 4;  int rr = rem & 15;
    int orow = g * 128 + w * 32 + tg * 16 + rr;
    int pk = __builtin_amdgcn_cvt_pk_fp8_f32(src[orow * HN + col], 0.f, 0, false);
    dst[idx] = (u8)(pk & 0xFF);
}

// ---------------- fp32 vector scale-copy
__global__ __launch_bounds__(256) void scale_copy(const float* __restrict__ src,
                                                  float* __restrict__ dst, int n, float scale)
{
    int i = blockIdx.x * blockDim.x + threadIdx.x;
    if (i < n) dst[i] = src[i] * scale;
}

// ---------------- x: fp32 [S][300] -> XF fp32 [S][320] + CUR bf16 [S][320]
__global__ __launch_bounds__(256) void pad_x(const float* __restrict__ src,
                                             float* __restrict__ xf, u16* __restrict__ cur)
{
    int n = SEQL * DP;
    for (int i = blockIdx.x * blockDim.x + threadIdx.x; i < n; i += gridDim.x * blockDim.x){
        int r = i / DP, c = i - r * DP;
        float v = (c < VECT) ? src[r * VECT + c] : 0.f;
        xf[i]  = v;
        cur[i] = f2bf(v);
    }
}

// ---------------- GEMM: Y[s][i][col] = sum_d A[s][i][d] * W[wsel][col][d] + bias[col]
// 256 thr = 4 waves; wave handles 16 rows; WG = 64 rows.
// OM: 1 = fp32 row-major; 3 = QKV fused (slices 0,1 row-major bf16, slice 2 transposed);
//     4 = fp32 with GRU gate-permuted columns: col = g*128+i  ->  i*3+g
template<int NT, int OM, bool WPERSEQ>
__global__ __launch_bounds__(256) void gemm_k(
    const u16* __restrict__ A, const u16* __restrict__ Wp,
    const float* __restrict__ b0, const float* __restrict__ b1, const float* __restrict__ b2,
    int nb, void* __restrict__ Out)
{
    const int lane = threadIdx.x & 63;
    const int wid  = threadIdx.x >> 6;
    const int s    = blockIdx.z;
    const int sl   = blockIdx.y;
    const int wsel = WPERSEQ ? s : sl;
    const int row0 = blockIdx.x * 64 + wid * 16;
    const int m    = lane & 15;
    const int q    = lane >> 4;

    const u16* Arow = A + ((long)s * SEQL + row0) * DP;
    const u16* W    = Wp + (long)wsel * (NT * 16) * DP;

    f32x4 zf = {0.f, 0.f, 0.f, 0.f};
    f32x4 acc[NT];
    #pragma unroll
    for (int n = 0; n < NT; n++) acc[n] = zf;

    for (int c = 0; c < DP / 32; ++c){
        const int koff = c * 32 + q * 8;
        bf16x8 a0 = *(const bf16x8*)(Arow + m * DP + koff);
        #pragma unroll
        for (int n = 0; n < NT; n++){
            bf16x8 b = *(const bf16x8*)(W + (n * 16 + m) * DP + koff);
            acc[n] = MFMA(a0, b, acc[n]);
        }
    }

    const int bsel = WPERSEQ ? s : sl;
    const float* bp = (bsel == 0) ? b0 : ((bsel == 1) ? b1 : b2);
    const long SLC = 2L * SEQL * DP;  // per-slice stride in QKV buffer

    #pragma unroll
    for (int n = 0; n < NT; n++){
        int col = n * 16 + m;
        float bv = (col < nb) ? bp[col] : 0.f;
        #pragma unroll
        for (int r = 0; r < 4; r++){
            long row = row0 + q * 4 + r;
            float v = acc[n][r] + bv;
            if (OM == 1){
                long off = ((long)s * SEQL + row) * (long)(NT * 16) + col;
                ((float*)Out)[off] = v;
            } else if (OM == 4){
                int g = col >> 7, i2 = col & 127;
                long off = ((long)s * SEQL + row) * (long)(NT * 16) + (i2 * 3 + g);
                ((float*)Out)[off] = v;
            } else {  // OM == 3
                long off;
                if (sl < 2) off = ((long)(sl * 2 + s) * SEQL + row) * DP + col;
                else        off = 2 * SLC + ((long)s * DP + col) * SEQL + row;
                ((u16*)Out)[off] = f2bf(v);
            }
        }
    }
}

// ---------------- flash attention chunk, LDS-tiled (r9 config — measured win)
__global__ __launch_bounds__(256, 1) void flash_k(
    const u16* __restrict__ Q, const u16* __restrict__ K, const u16* __restrict__ VT,
    u16* __restrict__ Onum, float* __restrict__ Lp)
{
    const int tid  = threadIdx.x;
    const int lane = tid & 63;
    const int wid  = tid >> 6;
    const int bid  = blockIdx.x;
    const int s    = bid & 1;
    const int jc   = (bid >> 1) & 3;
    const int xi   = bid >> 3;
    const int row0 = xi * 128 + wid * 32;
    const int m = lane & 15, q = lane >> 4;

    __shared__ __align__(16) u16 Kt[32 * KROW];
    __shared__ __align__(16) u16 Vt[DP * VROW];
    __shared__ __align__(16) u16 pb[4][2][16 * PROW];

    const u16* Qb = Q  + ((long)s * SEQL + row0) * DP;
    const u16* Kc = K  + (long)s * SEQL * DP + (long)jc * 1024 * DP;
    const u16* Vc = VT + (long)s * DP * SEQL + jc * 1024;

    bf16x8 qf0[10], qf1[10];
    #pragma unroll
    for (int c = 0; c < 10; c++){
        qf0[c] = *(const bf16x8*)(Qb + (m     ) * DP + c * 32 + q * 8);
        qf1[c] = *(const bf16x8*)(Qb + (m + 16) * DP + c * 32 + q * 8);
    }

    int skoff[5], wkoff[5], svoff[5], wvoff[5];
    #pragma unroll
    for (int it = 0; it < 5; it++){
        int f  = (it * 256 + tid) * 8;
        int rk = f / 320, ck = f - rk * 320;
        skoff[it] = f;
        wkoff[it] = rk * KROW + ck;
        int rv = f >> 5, cv = f & 31;
        svoff[it] = rv * SEQL + cv;
        wvoff[it] = rv * VROW + cv;
    }

    f32x4 zf = {0.f, 0.f, 0.f, 0.f};
    f32x4 oacc0[NQT], oacc1[NQT];
    #pragma unroll
    for (int n = 0; n < NQT; n++){ oacc0[n] = zf; oacc1[n] = zf; }
    float lacc0[4] = {0,0,0,0}, lacc1[4] = {0,0,0,0};

    const float K2 = 0.057735026918962576f * L2E;
    const float MB = -16.f * L2E;

    u32x4 kreg[5], vreg[5];
    #pragma unroll
    for (int it = 0; it < 5; it++){
        kreg[it] = *(const u32x4*)(Kc + skoff[it]);
        vreg[it] = *(const u32x4*)(Vc + svoff[it]);
    }
    #pragma unroll
    for (int it = 0; it < 5; it++){
        *(u32x4*)(&Kt[wkoff[it]]) = kreg[it];
        *(u32x4*)(&Vt[wvoff[it]]) = vreg[it];
    }
    __syncthreads();

    u16* pb0 = &pb[wid][0][0];
    u16* pb1 = &pb[wid][1][0];

    for (int j = 0; j < 32; ++j){
        if (j + 1 < 32){
            const u16* Kj = Kc + (j + 1) * 32 * DP;
            const u16* Vj = Vc + (j + 1) * 32;
            #pragma unroll
            for (int it = 0; it < 5; it++){
                kreg[it] = *(const u32x4*)(Kj + skoff[it]);
                vreg[it] = *(const u32x4*)(Vj + svoff[it]);
            }
        }
        f32x4 s0A = zf, s0B = zf, s1A = zf, s1B = zf;
        #pragma unroll
        for (int c = 0; c < 10; c++){
            bf16x8 kA = *(const bf16x8*)(&Kt[(m     ) * KROW + c * 32 + q * 8]);
            bf16x8 kB = *(const bf16x8*)(&Kt[(m + 16) * KROW + c * 32 + q * 8]);
            s0A = MFMA(qf0[c], kA, s0A);
            s0B = MFMA(qf0[c], kB, s0B);
            s1A = MFMA(qf1[c], kA, s1A);
            s1B = MFMA(qf1[c], kB, s1B);
        }
        #pragma unroll
        for (int r = 0; r < 4; r++){
            float a0 = __builtin_amdgcn_exp2f(fmaf(s0A[r], K2, MB));
            float b0 = __builtin_amdgcn_exp2f(fmaf(s0B[r], K2, MB));
            float a1 = __builtin_amdgcn_exp2f(fmaf(s1A[r], K2, MB));
            float b1 = __builtin_amdgcn_exp2f(fmaf(s1B[r], K2, MB));
            lacc0[r] += a0 + b0;
            lacc1[r] += a1 + b1;
            pb0[(q * 4 + r) * PROW +      m] = f2bf(a0);
            pb0[(q * 4 + r) * PROW + 16 + m] = f2bf(b0);
            pb1[(q * 4 + r) * PROW +      m] = f2bf(a1);
            pb1[(q * 4 + r) * PROW + 16 + m] = f2bf(b1);
        }
        bf16x8 pf0 = *(const bf16x8*)(&pb0[m * PROW + q * 8]);
        bf16x8 pf1 = *(const bf16x8*)(&pb1[m * PROW + q * 8]);
        #pragma unroll
        for (int n = 0; n < NQT; n++){
            bf16x8 vb = *(const bf16x8*)(&Vt[(n * 16 + m) * VROW + q * 8]);
            oacc0[n] = MFMA(pf0, vb, oacc0[n]);
            oacc1[n] = MFMA(pf1, vb, oacc1[n]);
        }
        __syncthreads();
        if (j + 1 < 32){
            #pragma unroll
            for (int it = 0; it < 5; it++){
                *(u32x4*)(&Kt[wkoff[it]]) = kreg[it];
                *(u32x4*)(&Vt[wvoff[it]]) = vreg[it];
            }
        }
        __syncthreads();
    }

    #pragma unroll
    for (int r = 0; r < 4; r++){
        float t0 = lacc0[r], t1 = lacc1[r];
        t0 += __shfl_xor(t0, 1); t0 += __shfl_xor(t0, 2);
        t0 += __shfl_xor(t0, 4); t0 += __shfl_xor(t0, 8);
        t1 += __shfl_xor(t1, 1); t1 += __shfl_xor(t1, 2);
        t1 += __shfl_xor(t1, 4); t1 += __shfl_xor(t1, 8);
        lacc0[r] = t0; lacc1[r] = t1;
    }
    const long grow0 = (long)s * SEQL + row0;
    if (m == 0){
        #pragma unroll
        for (int r = 0; r < 4; r++){
            Lp[(long)jc * 2 * SEQL + grow0 +      q * 4 + r] = lacc0[r];
            Lp[(long)jc * 2 * SEQL + grow0 + 16 + q * 4 + r] = lacc1[r];
        }
    }
    u16* Ob = Onum + ((long)jc * 2 * SEQL + grow0) * DP;
    #pragma unroll
    for (int n = 0; n < NQT; n++)
        #pragma unroll
        for (int r = 0; r < 4; r++){
            Ob[(long)(     q * 4 + r) * DP + n * 16 + m] = f2bf(oacc0[n][r]);
            Ob[(long)(16 + q * 4 + r) * DP + n * 16 + m] = f2bf(oacc1[n][r]);
        }
}

// ---------------- combine chunks + LayerNorm1: out = LN(sum(Onum)/sum(l) + XF) * g + b
__global__ __launch_bounds__(256) void lncomb_k(const u16* __restrict__ Onum, const float* __restrict__ Lp,
                                                const float* __restrict__ XF,
                                                const float* __restrict__ g, const float* __restrict__ b,
                                                u16* __restrict__ OutB)
{
    long row = (long)((blockIdx.x * blockDim.x + threadIdx.x) >> 6);
    int lane = threadIdx.x & 63;
    if (row >= 2L * SEQL) return;
    float l = 0.f;
    #pragma unroll
    for (int jc = 0; jc < JC; jc++) l += Lp[(long)jc * 2 * SEQL + row];
    float inv = 1.f / l;
    const float* xr = XF + row * DP;
    float v[5], sum = 0.f, sq = 0.f;
    #pragma unroll
    for (int i = 0; i < 5; i++){
        int c = lane + i * 64;
        float o = 0.f;
        #pragma unroll
        for (int jc = 0; jc < JC; jc++)
            o += bf2f(Onum[((long)jc * 2 * SEQL + row) * DP + c]);
        float t = (c < VECT) ? (o * inv + xr[c]) : 0.f;
        v[i] = t; sum += t; sq += t * t;
    }
    #pragma unroll
    for (int o = 1; o < 64; o <<= 1){ sum += __shfl_xor(sum, o); sq += __shfl_xor(sq, o); }
    float mean = sum / VECT;
    float var  = sq / VECT - mean * mean;
    float rstd = rsqrtf(var + 1e-5f);
    #pragma unroll
    for (int i = 0; i < 5; i++){
        int c = lane + i * 64;
        float t = (c < VECT) ? ((v[i] - mean) * rstd * g[c] + b[c]) : 0.f;
        OutB[row * DP + c] = f2bf(t);
    }
}

// ---------------- LayerNorm2: out = LN(Xf + Res) * g + b ; OutB bf16 + OutF fp32
__global__ __launch_bounds__(256) void ln_k(const float* __restrict__ Xf,
                                            const float* __restrict__ Res0, const float* __restrict__ Res1,
                                            int rstride,
                                            const float* __restrict__ g, const float* __restrict__ b,
                                            u16* __restrict__ OutB, float* __restrict__ OutF)
{
    long row = (long)((blockIdx.x * blockDim.x + threadIdx.x) >> 6);
    int lane = threadIdx.x & 63;
    if (row >= 2L * SEQL) return;
    const float* xr = Xf + row * DP;
    const float* rr = (row < SEQL) ? (Res0 + row * (long)rstride)
                                   : (Res1 + (row - SEQL) * (long)rstride);
    float v[5], sum = 0.f, sq = 0.f;
    #pragma unroll
    for (int i = 0; i < 5; i++){
        int c = lane + i * 64;
        float t = (c < VECT) ? (xr[c] + rr[c]) : 0.f;
        v[i] = t; sum += t; sq += t * t;
    }
    #pragma unroll
    for (int o = 1; o < 64; o <<= 1){ sum += __shfl_xor(sum, o); sq += __shfl_xor(sq, o); }
    float mean = sum / VECT;
    float var  = sq / VECT - mean * mean;
    float rstd = rsqrtf(var + 1e-5f);
    #pragma unroll
    for (int i = 0; i < 5; i++){
        int c = lane + i * 64;
        float t = (c < VECT) ? ((v[i] - mean) * rstd * g[c] + b[c]) : 0.f;
        OutB[row * DP + c] = f2bf(t);
        if (OutF) OutF[row * DP + c] = t;
    }
}

// ---------------- GRU: 1 WG/seq, 4 waves, ONE raw barrier/step, gates IN-REGISTER.
// W_hh rows permuted so wave w's 6 fp8 K=128 MFMA tiles are (r,z,n)x(2 groups) of ITS
// OWN 32 h-indices -> after the matvec every lane holds its index's (gh_r,gh_z,gh_n)
// in C-layout accs (cols replicated under broadcast-B). Lanes m<8 each own one index
// (static cndmask select), compute the gate chain pre-barrier, and write ONE fp8 h byte.
// Exchange payload = 128 B double-buffered; gx permuted (triples) with distance-2
// prefetch via manual unroll-2 two-register-set pipeline (no rotation movs -> the
// compiler's vmcnt wait lands ~2 steps after issue, covering HBM latency).
__global__ __launch_bounds__(256, 1) void gru_k(
    const float* __restrict__ GXP,                         // [2][SEQL][384] fp32, permuted i*3+g
    const u8* __restrict__ Whh8p,                          // [2][384][128] fp8, permuted rows
    const float* __restrict__ Bhh1, const float* __restrict__ Bhh2,
    float* __restrict__ Hout)                              // [2][128] fp32
{
    const int s = blockIdx.x;
    const int tid = threadIdx.x;
    const int lane = tid & 63;
    const int wid  = tid >> 6;
    const int m = lane & 15, q = lane >> 4;
    const u8* Whh = Whh8p + (long)s * G3 * HN;
    const float* Bhh = s ? Bhh2 : Bhh1;
    const float* gx = GXP + (long)s * SEQL * G3;

    __shared__ __align__(8) u8 hst[2][HN];     // double-buffered fp8 h

    // A-frags: t6 = tg*3+g, prow = wid*96 + tg*48 + g*16 + m, k-bytes q*32..+31
    v8i af[6];
    #pragma unroll
    for (int tg = 0; tg < 2; tg++)
        #pragma unroll
        for (int g = 0; g < 3; g++)
            af[tg * 3 + g] = *(const v8i*)(Whh + (long)(wid * 96 + tg * 48 + g * 16 + m) * HN + q * 32);

    const int tgl  = (m >> 2) & 1;
    const int rsel = m & 3;
    const int il   = wid * 32 + tgl * 16 + q * 4 + rsel;   // this lane's h index
    const int il3  = il * 3;
    const float bhr = Bhh[il], bhz = Bhh[HN + il], bhn = Bhh[2 * HN + il];

    if (tid < HN){ hst[0][tid] = 0; hst[1][tid] = 0; }

    // gx pipeline: set0 = t0, set1 = t1 (each set reloaded in-place with t+2's data)
    const float* ga = gx + il3;
    float cr0 = ga[0], cz0 = ga[1], cn0 = ga[2];
    const float* gb = gx + G3 + il3;
    float cr1 = gb[0], cz1 = gb[1], cn1 = gb[2];

    __syncthreads();

    float h = 0.f;
    const f32x4 zf = {0.f, 0.f, 0.f, 0.f};

#define GRU_STEP(T, CR, CZ, CN, WB, RB)                                               \
    {                                                                                 \
        v8i bfrag = *(const v8i*)(&hst[RB][q * 32]);                                  \
        f32x4 a0 = __builtin_amdgcn_mfma_scale_f32_16x16x128_f8f6f4(af[0], bfrag, zf, 0, 0, 0, 127, 0, 127); \
        f32x4 a1 = __builtin_amdgcn_mfma_scale_f32_16x16x128_f8f6f4(af[1], bfrag, zf, 0, 0, 0, 127, 0, 127); \
        f32x4 a2 = __builtin_amdgcn_mfma_scale_f32_16x16x128_f8f6f4(af[2], bfrag, zf, 0, 0, 0, 127, 0, 127); \
        f32x4 a3 = __builtin_amdgcn_mfma_scale_f32_16x16x128_f8f6f4(af[3], bfrag, zf, 0, 0, 0, 127, 0, 127); \
        f32x4 a4 = __builtin_amdgcn_mfma_scale_f32_16x16x128_f8f6f4(af[4], bfrag, zf, 0, 0, 0, 127, 0, 127); \
        f32x4 a5 = __builtin_amdgcn_mfma_scale_f32_16x16x128_f8f6f4(af[5], bfrag, zf, 0, 0, 0, 127, 0, 127); \
        float ghr = sel4(tgl ? a3 : a0, rsel);                                        \
        float ghz = sel4(tgl ? a4 : a1, rsel);                                        \
        float ghn = sel4(tgl ? a5 : a2, rsel);                                        \
        float rg = sigm_f(CR + ghr + bhr);                                            \
        float zg = sigm_f(CZ + ghz + bhz);                                            \
        float ng = tanh_f(CN + rg * (ghn + bhn));                                     \
        h = (1.f - zg) * ng + zg * h;                                                 \
        if (m < 8){                                                                   \
            int pk = __builtin_amdgcn_cvt_pk_fp8_f32(h, h, 0, false);                 \
            hst[WB][il] = (u8)(pk & 0xFF);                                            \
        }                                                                             \
        int tp = ((T) + 2 < SEQL) ? (T) + 2 : SEQL - 1;                               \
        const float* gp = gx + (long)tp * G3 + il3;                                   \
        CR = gp[0]; CZ = gp[1]; CN = gp[2];                                           \
        asm volatile("s_waitcnt lgkmcnt(0)" ::: "memory");                            \
        __builtin_amdgcn_s_barrier();                                                 \
        asm volatile("" ::: "memory");                                                \
    }

    for (int t = 0; t < SEQL; t += 2){
        GRU_STEP(t,     cr0, cz0, cn0, 0, 1);
        GRU_STEP(t + 1, cr1, cz1, cn1, 1, 0);
    }
#undef GRU_STEP

    if (m < 8) Hout[s * HN + il] = h;
}

// ---------------- head: fc1+relu, fc2, log_softmax -> 3 fp32
__global__ __launch_bounds__(256) void final_k(const float* __restrict__ Hout,
                                               const float* __restrict__ fc1w, const float* __restrict__ fc1b,
                                               const float* __restrict__ fc2w, const float* __restrict__ fc2b,
                                               float* __restrict__ out)
{
    __shared__ float hb[256];
    __shared__ float r1[256];
    __shared__ float lg[3];
    int tid = threadIdx.x;
    hb[tid] = Hout[tid];
    __syncthreads();
    float a = 0.f;
    for (int k2 = 0; k2 < 256; k2++) a += hb[k2] * fc1w[tid * 256 + k2];
    a += fc1b[tid];
    r1[tid] = fmaxf(a, 0.f);
    __syncthreads();
    if (tid < 3){
        float v = 0.f;
        for (int k2 = 0; k2 < 256; k2++) v += r1[k2] * fc2w[tid * 256 + k2];
        lg[tid] = v + fc2b[tid];
    }
    __syncthreads();
    if (tid == 0){
        float mx = fmaxf(lg[0], fmaxf(lg[1], lg[2]));
        float se = __expf(lg[0] - mx) + __expf(lg[1] - mx) + __expf(lg[2] - mx);
        float ls = mx + logf(se);
        out[0] = lg[0] - ls;
        out[1] = lg[1] - ls;
        out[2] = lg[2] - ls;
    }
}

extern "C" void kernel_launch(void* const* d_in, const int* in_sizes, int n_in,
                              void* d_out, int out_size, void* d_ws, size_t ws_size,
                              hipStream_t stream)
{
    (void)in_sizes; (void)n_in; (void)out_size; (void)ws_size;
    const float* x1     = (const float*)d_in[0];
    const float* x2     = (const float*)d_in[1];
    const float* q_w    = (const float*)d_in[2],  *q_b   = (const float*)d_in[3];
    const float* k_w    = (const float*)d_in[4],  *k_b   = (const float*)d_in[5];
    const float* v_w    = (const float*)d_in[6],  *v_b   = (const float*)d_in[7];
    const float* aln_g  = (const float*)d_in[8],  *aln_b = (const float*)d_in[9];
    const float* w_w    = (const float*)d_in[10], *w_b   = (const float*)d_in[11];
    const float* mln_g  = (const float*)d_in[12], *mln_b = (const float*)d_in[13];
    const float* g1_wih = (const float*)d_in[14], *g1_whh = (const float*)d_in[15];
    const float* g1_bih = (const float*)d_in[16], *g1_bhh = (const float*)d_in[17];
    const float* g2_wih = (const float*)d_in[18], *g2_whh = (const float*)d_in[19];
    const float* g2_bih = (const float*)d_in[20], *g2_bhh = (const float*)d_in[21];
    const float* fc1w   = (const float*)d_in[22], *fc1b  = (const float*)d_in[23];
    const float* fc2w   = (const float*)d_in[24], *fc2b  = (const float*)d_in[25];

    char* wsp = (char*)d_ws;
    auto alloc = [&](size_t bytes) -> char* {
        char* p = wsp; wsp += (bytes + 255) & ~(size_t)255; return p;
    };
    float* XF   = (float*)alloc(2L * SEQL * DP * 4);   // fp32 stack input (residual for aln)
    u16*   CUR  = (u16*)  alloc(2L * SEQL * DP * 2);   // bf16 stack input (MFMA operand)
    u16*   Hb   = (u16*)  alloc(2L * SEQL * DP * 2);   // LN1 output bf16
    u16*   Wpk  = (u16*)  alloc(4L * DP * DP * 2);     // q,k,v,w packed bf16 [320][320]
    u16*   GWpk = (u16*)  alloc(2L * G3 * DP * 2);     // g{1,2}_wih packed bf16 [384][320]
    u8*    Whh8 = (u8*)   alloc(2L * G3 * HN);         // g{1,2}_whh fp8, gate-permuted rows
    float* qbS  = (float*)alloc(DP * 4);               // q bias copy
    float* Hout = (float*)alloc(2L * HN * 4);
    float* Lp   = (float*)alloc((long)JC * 2 * SEQL * 4);
    // union1: {QK 2 slices + VT} vs GX (permuted gate-triple layout)
    size_t u1 = (2L * 2 * SEQL * DP + 2L * DP * SEQL) * 2;
    size_t u1b = 2L * SEQL * G3 * 4;
    u16*   QKV  = (u16*)  alloc(u1 > u1b ? u1 : u1b);
    u16*   VT   = QKV + 2L * 2 * SEQL * DP;
    float* GX   = (float*)QKV;
    // union2: Onum (flash numerator partials, bf16) vs Of (fp32 W-proj out)
    size_t u2 = (long)JC * 2 * SEQL * DP * 2;
    size_t u2b = 2L * SEQL * DP * 4;
    u16*   Onum = (u16*)  alloc(u2 > u2b ? u2 : u2b);
    float* Of   = (float*)Onum;

    // prep
    pad_x<<<256, 256, 0, stream>>>(x1, XF,                  CUR);
    pad_x<<<256, 256, 0, stream>>>(x2, XF + (long)SEQL*DP,  CUR + (long)SEQL*DP);
    cvt_pad<<<128, 256, 0, stream>>>(q_w, Wpk,                VECT, VECT, DP, DP, 1.f);
    cvt_pad<<<128, 256, 0, stream>>>(k_w, Wpk + 1L * DP * DP, VECT, VECT, DP, DP, 1.f);
    cvt_pad<<<128, 256, 0, stream>>>(v_w, Wpk + 2L * DP * DP, VECT, VECT, DP, DP, 1.f);
    cvt_pad<<<128, 256, 0, stream>>>(w_w, Wpk + 3L * DP * DP, VECT, VECT, DP, DP, 1.f);
    cvt_pad<<<128, 256, 0, stream>>>(g1_wih, GWpk,                 G3, VECT, G3, DP, 1.f);
    cvt_pad<<<128, 256, 0, stream>>>(g2_wih, GWpk + (long)G3 * DP, G3, VECT, G3, DP, 1.f);
    cvt_whh<<<192, 256, 0, stream>>>(g1_whh, Whh8);
    cvt_whh<<<192, 256, 0, stream>>>(g2_whh, Whh8 + (long)G3 * HN);
    scale_copy<<<2, 256, 0, stream>>>(q_b, qbS, VECT, 1.f);

    for (int st = 0; st < 3; ++st){
        // Q,K -> QKV slices 0,1 ; V -> transposed at slice 2 (VT)
        gemm_k<NQT, 3, false><<<dim3(SEQL / 64, 3, 2), 256, 0, stream>>>(
            CUR, Wpk, qbS, k_b, v_b, VECT, QKV);
        flash_k<<<dim3(256), 256, 0, stream>>>(QKV, QKV + 2L*SEQL*DP, VT, Onum, Lp);
        lncomb_k<<<dim3(2 * SEQL / 4), 256, 0, stream>>>(Onum, Lp, XF, aln_g, aln_b, Hb);
        gemm_k<NQT, 1, false><<<dim3(SEQL / 64, 1, 2), 256, 0, stream>>>(
            Hb, Wpk + 3L * DP * DP, w_b, nullptr, nullptr, VECT, Of);
        ln_k<<<dim3(2 * SEQL / 4), 256, 0, stream>>>(Of, x1, x2, VECT, mln_g, mln_b, CUR, XF);
    }

    // GRU input projections, gate-permuted output (weight/bias per seq) -> GX
    gemm_k<24, 4, true><<<dim3(SEQL / 64, 1, 2), 256, 0, stream>>>(
        CUR, GWpk, g1_bih, g2_bih, nullptr, G3, GX);
    gru_k<<<dim3(2), 256, 0, stream>>>(GX, Whh8, g1_bhh, g2_bhh, Hout);
    final_k<<<dim3(1), 256, 0, stream>>>(Hout, fc1w, fc1b, fc2w, fc2b, (float*)d_out);
}

// Round 11
// 2025.580 us; speedup vs baseline: 2.0796x; 1.0370x over previous
//
#include <hip/hip_runtime.h>
#include <hip/hip_bf16.h>

// Problem constants
#define SEQL 4096
#define VECT 300
#define DP   320     // padded feature dim (k-dim), 10 chunks of 32
#define NQT  20      // n-tiles (320 cols) for projection GEMMs
#define HN   128
#define G3   384     // 3*H
#define JC   4       // flash j-chunks (split-K over key dim)
#define KROW 328     // LDS K-tile row stride (u16)
#define VROW 40      // LDS VT-tile row stride (u16)
#define PROW 40      // pbuf row stride

typedef unsigned short u16;
typedef unsigned char  u8;
typedef __attribute__((ext_vector_type(8))) short bf16x8;  // 8 bf16 = 4 VGPRs
typedef __attribute__((ext_vector_type(4))) float f32x4;
typedef __attribute__((ext_vector_type(4))) unsigned int u32x4;
typedef __attribute__((ext_vector_type(8))) int   v8i;     // 8 dwords (fp8 x32)

#define MFMA(a,b,c) __builtin_amdgcn_mfma_f32_16x16x32_bf16(a,b,c,0,0,0)
// Verified layouts (learn_hip m89/m91/m120):
//   A[m][k]: m=lane&15, k=(lane>>4)*8+j
//   B[k][n]: n=lane&15, k=(lane>>4)*8+j
//   C/D[row][col]: col=lane&15, row=(lane>>4)*4+reg

#define L2E 1.44269504088896f

#define RAW_BAR() do {                                          \
    asm volatile("s_waitcnt lgkmcnt(0)" ::: "memory");          \
    __builtin_amdgcn_s_barrier();                               \
    asm volatile("" ::: "memory");                              \
} while (0)

__device__ __forceinline__ float bf2f(u16 v){
    union { unsigned u; float f; } t; t.u = ((unsigned)v) << 16; return t.f;
}
__device__ __forceinline__ u16 f2bf(float f){
    union { float f; unsigned u; } t; t.f = f;
    return (u16)((t.u + 0x7FFFu + ((t.u >> 16) & 1u)) >> 16);
}
__device__ __forceinline__ float sigm_f(float x){
    return __builtin_amdgcn_rcpf(1.f + __builtin_amdgcn_exp2f(-L2E * x));
}
__device__ __forceinline__ float tanh_f(float x){
    return fmaf(2.f, __builtin_amdgcn_rcpf(1.f + __builtin_amdgcn_exp2f(-2.f * L2E * x)), -1.f);
}
__device__ __forceinline__ float sel4(f32x4 v, int r){
    float a = (r & 1) ? v.y : v.x;
    float b = (r & 1) ? v.w : v.z;
    return (r & 2) ? b : a;
}

// ---------------- fused prep: x pad (y selects seq)
__global__ __launch_bounds__(256) void pad_x2(const float* __restrict__ x1, const float* __restrict__ x2,
                                              float* __restrict__ xf, u16* __restrict__ cur)
{
    int s = blockIdx.y;
    const float* src = s ? x2 : x1;
    float* xfo = xf + (long)s * SEQL * DP;
    u16*  cro = cur + (long)s * SEQL * DP;
    int n = SEQL * DP;
    for (int i = blockIdx.x * blockDim.x + threadIdx.x; i < n; i += gridDim.x * blockDim.x){
        int r = i / DP, c = i - r * DP;
        float v = (c < VECT) ? src[r * VECT + c] : 0.f;
        xfo[i] = v;
        cro[i] = f2bf(v);
    }
}

// ---------------- fused prep: 4 attention weights -> Wpk (y selects which)
__global__ __launch_bounds__(256) void cvt_pad_w4(const float* __restrict__ w0, const float* __restrict__ w1,
                                                  const float* __restrict__ w2, const float* __restrict__ w3,
                                                  u16* __restrict__ Wpk)
{
    int sl = blockIdx.y;
    const float* src = (sl == 0) ? w0 : (sl == 1) ? w1 : (sl == 2) ? w2 : w3;
    u16* dst = Wpk + (long)sl * DP * DP;
    int n = DP * DP;
    for (int i = blockIdx.x * blockDim.x + threadIdx.x; i < n; i += gridDim.x * blockDim.x){
        int r = i / DP, c = i - r * DP;
        float v = (r < VECT && c < VECT) ? src[r * VECT + c] : 0.f;
        dst[i] = f2bf(v);
    }
}

// ---------------- fused prep: 2 GRU input weights -> GWpk (y selects)
__global__ __launch_bounds__(256) void cvt_pad_g2(const float* __restrict__ w0, const float* __restrict__ w1,
                                                  u16* __restrict__ GWpk)
{
    int s = blockIdx.y;
    const float* src = s ? w1 : w0;
    u16* dst = GWpk + (long)s * G3 * DP;
    int n = G3 * DP;
    for (int i = blockIdx.x * blockDim.x + threadIdx.x; i < n; i += gridDim.x * blockDim.x){
        int r = i / DP, c = i - r * DP;
        float v = (c < VECT) ? src[r * VECT + c] : 0.f;
        dst[i] = f2bf(v);
    }
}

// ---------------- fused prep: Whh fp32 [384][128] -> fp8, gate-permuted rows (y selects seq)
// prow = w*96 + tg*48 + g*16 + rr  <->  orig row g*128 + (w*32 + tg*16 + rr)
__global__ __launch_bounds__(256) void cvt_whh2(const float* __restrict__ w0, const float* __restrict__ w1,
                                                u8* __restrict__ dst0)
{
    int s = blockIdx.y;
    const float* src = s ? w1 : w0;
    u8* dst = dst0 + (long)s * G3 * HN;
    int idx = blockIdx.x * 256 + threadIdx.x;
    if (idx >= G3 * HN) return;
    int prow = idx >> 7, col = idx & 127;
    int w  = prow / 96, rem = prow - w * 96;
    int tg = rem / 48;  rem -= tg * 48;
    int g  = rem >> 4;  int rr = rem & 15;
    int orow = g * 128 + w * 32 + tg * 16 + rr;
    int pk = __builtin_amdgcn_cvt_pk_fp8_f32(src[orow * HN + col], 0.f, 0, false);
    dst[idx] = (u8)(pk & 0xFF);
}

// ---------------- GEMM: Y[s][i][col] = sum_d A[s][i][d] * W[wsel][col][d] + bias[col]
// 256 thr = 4 waves; wave handles 16 rows; WG = 64 rows.
// OM: 3 = QKV fused (slices 0,1 row-major bf16, slice 2 transposed);
//     4 = fp32 with GRU gate-permuted columns: col = g*128+i -> i*3+g
template<int NT, int OM, bool WPERSEQ>
__global__ __launch_bounds__(256) void gemm_k(
    const u16* __restrict__ A, const u16* __restrict__ Wp,
    const float* __restrict__ b0, const float* __restrict__ b1, const float* __restrict__ b2,
    int nb, void* __restrict__ Out)
{
    const int lane = threadIdx.x & 63;
    const int wid  = threadIdx.x >> 6;
    const int s    = blockIdx.z;
    const int sl   = blockIdx.y;
    const int wsel = WPERSEQ ? s : sl;
    const int row0 = blockIdx.x * 64 + wid * 16;
    const int m    = lane & 15;
    const int q    = lane >> 4;

    const u16* Arow = A + ((long)s * SEQL + row0) * DP;
    const u16* W    = Wp + (long)wsel * (NT * 16) * DP;

    f32x4 zf = {0.f, 0.f, 0.f, 0.f};
    f32x4 acc[NT];
    #pragma unroll
    for (int n = 0; n < NT; n++) acc[n] = zf;

    for (int c = 0; c < DP / 32; ++c){
        const int koff = c * 32 + q * 8;
        bf16x8 a0 = *(const bf16x8*)(Arow + m * DP + koff);
        #pragma unroll
        for (int n = 0; n < NT; n++){
            bf16x8 b = *(const bf16x8*)(W + (n * 16 + m) * DP + koff);
            acc[n] = MFMA(a0, b, acc[n]);
        }
    }

    const int bsel = WPERSEQ ? s : sl;
    const float* bp = (bsel == 0) ? b0 : ((bsel == 1) ? b1 : b2);
    const long SLC = 2L * SEQL * DP;  // per-slice stride in QKV buffer

    #pragma unroll
    for (int n = 0; n < NT; n++){
        int col = n * 16 + m;
        float bv = (col < nb) ? bp[col] : 0.f;
        #pragma unroll
        for (int r = 0; r < 4; r++){
            long row = row0 + q * 4 + r;
            float v = acc[n][r] + bv;
            if (OM == 4){
                int g = col >> 7, i2 = col & 127;
                long off = ((long)s * SEQL + row) * (long)(NT * 16) + (i2 * 3 + g);
                ((float*)Out)[off] = v;
            } else {  // OM == 3
                long off;
                if (sl < 2) off = ((long)(sl * 2 + s) * SEQL + row) * DP + col;
                else        off = 2 * SLC + ((long)s * DP + col) * SEQL + row;
                ((u16*)Out)[off] = f2bf(v);
            }
        }
    }
}

// ---------------- fused W-projection + residual + LayerNorm2:
// CUR/XF[row] = LN(Hb[row] @ W^T + w_b + x[row]) * g + b   (bf16 + fp32 outputs)
// Wave owns 16 complete rows x all 320 cols -> LN stats via 4-bit m-shuffles in epilogue.
__global__ __launch_bounds__(256) void gemmln_k(
    const u16* __restrict__ A, const u16* __restrict__ Wp, const float* __restrict__ bias,
    const float* __restrict__ res0, const float* __restrict__ res1,
    const float* __restrict__ g, const float* __restrict__ b,
    u16* __restrict__ OutB, float* __restrict__ OutF)
{
    const int lane = threadIdx.x & 63;
    const int wid  = threadIdx.x >> 6;
    const int s    = blockIdx.z;
    const int row0 = blockIdx.x * 64 + wid * 16;
    const int m    = lane & 15;
    const int q    = lane >> 4;

    const u16* Arow = A + ((long)s * SEQL + row0) * DP;
    const float* res = s ? res1 : res0;

    f32x4 zf = {0.f, 0.f, 0.f, 0.f};
    f32x4 acc[NQT];
    #pragma unroll
    for (int n = 0; n < NQT; n++) acc[n] = zf;

    for (int c = 0; c < DP / 32; ++c){
        const int koff = c * 32 + q * 8;
        bf16x8 a0 = *(const bf16x8*)(Arow + m * DP + koff);
        #pragma unroll
        for (int n = 0; n < NQT; n++){
            bf16x8 bb = *(const bf16x8*)(Wp + (n * 16 + m) * DP + koff);
            acc[n] = MFMA(a0, bb, acc[n]);
        }
    }

    // add bias + residual; accumulate LN stats per row (r)
    float sum[4] = {0,0,0,0}, sq[4] = {0,0,0,0};
    #pragma unroll
    for (int n = 0; n < NQT; n++){
        int col = n * 16 + m;
        float bv = (col < VECT) ? bias[col] : 0.f;
        #pragma unroll
        for (int r = 0; r < 4; r++){
            long row = row0 + q * 4 + r;
            float rr = (col < VECT) ? res[row * VECT + col] : 0.f;
            float t = (col < VECT) ? (acc[n][r] + bv + rr) : 0.f;
            acc[n][r] = t;
            sum[r] += t; sq[r] += t * t;
        }
    }
    #pragma unroll
    for (int r = 0; r < 4; r++){
        float su = sum[r], sv = sq[r];
        su += __shfl_xor(su, 1); sv += __shfl_xor(sv, 1);
        su += __shfl_xor(su, 2); sv += __shfl_xor(sv, 2);
        su += __shfl_xor(su, 4); sv += __shfl_xor(sv, 4);
        su += __shfl_xor(su, 8); sv += __shfl_xor(sv, 8);
        sum[r] = su; sq[r] = sv;
    }
    float mean[4], rstd[4];
    #pragma unroll
    for (int r = 0; r < 4; r++){
        mean[r] = sum[r] / VECT;
        float var = sq[r] / VECT - mean[r] * mean[r];
        rstd[r] = rsqrtf(var + 1e-5f);
    }
    #pragma unroll
    for (int n = 0; n < NQT; n++){
        int col = n * 16 + m;
        float gv = (col < VECT) ? g[col] : 0.f;
        float bv = (col < VECT) ? b[col] : 0.f;
        #pragma unroll
        for (int r = 0; r < 4; r++){
            long row = (long)s * SEQL + row0 + q * 4 + r;
            float t = (col < VECT) ? ((acc[n][r] - mean[r]) * rstd[r] * gv + bv) : 0.f;
            OutB[row * DP + col] = f2bf(t);
            OutF[row * DP + col] = t;
        }
    }
}

// ---------------- flash attention chunk, LDS-tiled (r9/r10 config, raw lgkm barriers)
__global__ __launch_bounds__(256, 1) void flash_k(
    const u16* __restrict__ Q, const u16* __restrict__ K, const u16* __restrict__ VT,
    u16* __restrict__ Onum, float* __restrict__ Lp)
{
    const int tid  = threadIdx.x;
    const int lane = tid & 63;
    const int wid  = tid >> 6;
    const int bid  = blockIdx.x;
    const int s    = bid & 1;
    const int jc   = (bid >> 1) & 3;
    const int xi   = bid >> 3;
    const int row0 = xi * 128 + wid * 32;
    const int m = lane & 15, q = lane >> 4;

    __shared__ __align__(16) u16 Kt[32 * KROW];
    __shared__ __align__(16) u16 Vt[DP * VROW];
    __shared__ __align__(16) u16 pb[4][2][16 * PROW];

    const u16* Qb = Q  + ((long)s * SEQL + row0) * DP;
    const u16* Kc = K  + (long)s * SEQL * DP + (long)jc * 1024 * DP;
    const u16* Vc = VT + (long)s * DP * SEQL + jc * 1024;

    bf16x8 qf0[10], qf1[10];
    #pragma unroll
    for (int c = 0; c < 10; c++){
        qf0[c] = *(const bf16x8*)(Qb + (m     ) * DP + c * 32 + q * 8);
        qf1[c] = *(const bf16x8*)(Qb + (m + 16) * DP + c * 32 + q * 8);
    }

    int skoff[5], wkoff[5], svoff[5], wvoff[5];
    #pragma unroll
    for (int it = 0; it < 5; it++){
        int f  = (it * 256 + tid) * 8;
        int rk = f / 320, ck = f - rk * 320;
        skoff[it] = f;
        wkoff[it] = rk * KROW + ck;
        int rv = f >> 5, cv = f & 31;
        svoff[it] = rv * SEQL + cv;
        wvoff[it] = rv * VROW + cv;
    }

    f32x4 zf = {0.f, 0.f, 0.f, 0.f};
    f32x4 oacc0[NQT], oacc1[NQT];
    #pragma unroll
    for (int n = 0; n < NQT; n++){ oacc0[n] = zf; oacc1[n] = zf; }
    float lacc0[4] = {0,0,0,0}, lacc1[4] = {0,0,0,0};

    const float K2 = 0.057735026918962576f * L2E;
    const float MB = -16.f * L2E;

    u32x4 kreg[5], vreg[5];
    #pragma unroll
    for (int it = 0; it < 5; it++){
        kreg[it] = *(const u32x4*)(Kc + skoff[it]);
        vreg[it] = *(const u32x4*)(Vc + svoff[it]);
    }
    #pragma unroll
    for (int it = 0; it < 5; it++){
        *(u32x4*)(&Kt[wkoff[it]]) = kreg[it];
        *(u32x4*)(&Vt[wvoff[it]]) = vreg[it];
    }
    RAW_BAR();

    u16* pb0 = &pb[wid][0][0];
    u16* pb1 = &pb[wid][1][0];

    for (int j = 0; j < 32; ++j){
        if (j + 1 < 32){
            const u16* Kj = Kc + (j + 1) * 32 * DP;
            const u16* Vj = Vc + (j + 1) * 32;
            #pragma unroll
            for (int it = 0; it < 5; it++){
                kreg[it] = *(const u32x4*)(Kj + skoff[it]);
                vreg[it] = *(const u32x4*)(Vj + svoff[it]);
            }
        }
        f32x4 s0A = zf, s0B = zf, s1A = zf, s1B = zf;
        #pragma unroll
        for (int c = 0; c < 10; c++){
            bf16x8 kA = *(const bf16x8*)(&Kt[(m     ) * KROW + c * 32 + q * 8]);
            bf16x8 kB = *(const bf16x8*)(&Kt[(m + 16) * KROW + c * 32 + q * 8]);
            s0A = MFMA(qf0[c], kA, s0A);
            s0B = MFMA(qf0[c], kB, s0B);
            s1A = MFMA(qf1[c], kA, s1A);
            s1B = MFMA(qf1[c], kB, s1B);
        }
        #pragma unroll
        for (int r = 0; r < 4; r++){
            float a0 = __builtin_amdgcn_exp2f(fmaf(s0A[r], K2, MB));
            float b0 = __builtin_amdgcn_exp2f(fmaf(s0B[r], K2, MB));
            float a1 = __builtin_amdgcn_exp2f(fmaf(s1A[r], K2, MB));
            float b1 = __builtin_amdgcn_exp2f(fmaf(s1B[r], K2, MB));
            lacc0[r] += a0 + b0;
            lacc1[r] += a1 + b1;
            pb0[(q * 4 + r) * PROW +      m] = f2bf(a0);
            pb0[(q * 4 + r) * PROW + 16 + m] = f2bf(b0);
            pb1[(q * 4 + r) * PROW +      m] = f2bf(a1);
            pb1[(q * 4 + r) * PROW + 16 + m] = f2bf(b1);
        }
        bf16x8 pf0 = *(const bf16x8*)(&pb0[m * PROW + q * 8]);
        bf16x8 pf1 = *(const bf16x8*)(&pb1[m * PROW + q * 8]);
        #pragma unroll
        for (int n = 0; n < NQT; n++){
            bf16x8 vb = *(const bf16x8*)(&Vt[(n * 16 + m) * VROW + q * 8]);
            oacc0[n] = MFMA(pf0, vb, oacc0[n]);
            oacc1[n] = MFMA(pf1, vb, oacc1[n]);
        }
        RAW_BAR();                    // all waves done reading Kt/Vt for j
        if (j + 1 < 32){
            #pragma unroll
            for (int it = 0; it < 5; it++){
                *(u32x4*)(&Kt[wkoff[it]]) = kreg[it];
                *(u32x4*)(&Vt[wvoff[it]]) = vreg[it];
            }
        }
        RAW_BAR();                    // tiles for j+1 published
    }

    #pragma unroll
    for (int r = 0; r < 4; r++){
        float t0 = lacc0[r], t1 = lacc1[r];
        t0 += __shfl_xor(t0, 1); t0 += __shfl_xor(t0, 2);
        t0 += __shfl_xor(t0, 4); t0 += __shfl_xor(t0, 8);
        t1 += __shfl_xor(t1, 1); t1 += __shfl_xor(t1, 2);
        t1 += __shfl_xor(t1, 4); t1 += __shfl_xor(t1, 8);
        lacc0[r] = t0; lacc1[r] = t1;
    }
    const long grow0 = (long)s * SEQL + row0;
    if (m == 0){
        #pragma unroll
        for (int r = 0; r < 4; r++){
            Lp[(long)jc * 2 * SEQL + grow0 +      q * 4 + r] = lacc0[r];
            Lp[(long)jc * 2 * SEQL + grow0 + 16 + q * 4 + r] = lacc1[r];
        }
    }
    u16* Ob = Onum + ((long)jc * 2 * SEQL + grow0) * DP;
    #pragma unroll
    for (int n = 0; n < NQT; n++)
        #pragma unroll
        for (int r = 0; r < 4; r++){
            Ob[(long)(     q * 4 + r) * DP + n * 16 + m] = f2bf(oacc0[n][r]);
            Ob[(long)(16 + q * 4 + r) * DP + n * 16 + m] = f2bf(oacc1[n][r]);
        }
}

// ---------------- combine chunks + LayerNorm1: out = LN(sum(Onum)/sum(l) + XF) * g + b
__global__ __launch_bounds__(256) void lncomb_k(const u16* __restrict__ Onum, const float* __restrict__ Lp,
                                                const float* __restrict__ XF,
                                                const float* __restrict__ g, const float* __restrict__ b,
                                                u16* __restrict__ OutB)
{
    long row = (long)((blockIdx.x * blockDim.x + threadIdx.x) >> 6);
    int lane = threadIdx.x & 63;
    if (row >= 2L * SEQL) return;
    float l = 0.f;
    #pragma unroll
    for (int jc = 0; jc < JC; jc++) l += Lp[(long)jc * 2 * SEQL + row];
    float inv = 1.f / l;
    const float* xr = XF + row * DP;
    float v[5], sum = 0.f, sq = 0.f;
    #pragma unroll
    for (int i = 0; i < 5; i++){
        int c = lane + i * 64;
        float o = 0.f;
        #pragma unroll
        for (int jc = 0; jc < JC; jc++)
            o += bf2f(Onum[((long)jc * 2 * SEQL + row) * DP + c]);
        float t = (c < VECT) ? (o * inv + xr[c]) : 0.f;
        v[i] = t; sum += t; sq += t * t;
    }
    #pragma unroll
    for (int o = 1; o < 64; o <<= 1){ sum += __shfl_xor(sum, o); sq += __shfl_xor(sq, o); }
    float mean = sum / VECT;
    float var  = sq / VECT - mean * mean;
    float rstd = rsqrtf(var + 1e-5f);
    #pragma unroll
    for (int i = 0; i < 5; i++){
        int c = lane + i * 64;
        float t = (c < VECT) ? ((v[i] - mean) * rstd * g[c] + b[c]) : 0.f;
        OutB[row * DP + c] = f2bf(t);
    }
}

// ---------------- GRU (r10 config — measured win): 1 WG/seq, 4 waves, ONE raw barrier/step,
// gates in-register via gate-permuted fp8 K=128 MFMA; 128 B double-buffered h exchange.
__global__ __launch_bounds__(256, 1) void gru_k(
    const float* __restrict__ GXP,                         // [2][SEQL][384] fp32, permuted i*3+g
    const u8* __restrict__ Whh8p,                          // [2][384][128] fp8, permuted rows
    const float* __restrict__ Bhh1, const float* __restrict__ Bhh2,
    float* __restrict__ Hout)                              // [2][128] fp32
{
    const int s = blockIdx.x;
    const int tid = threadIdx.x;
    const int lane = tid & 63;
    const int wid  = tid >> 6;
    const int m = lane & 15, q = lane >> 4;
    const u8* Whh = Whh8p + (long)s * G3 * HN;
    const float* Bhh = s ? Bhh2 : Bhh1;
    const float* gx = GXP + (long)s * SEQL * G3;

    __shared__ __align__(8) u8 hst[2][HN];     // double-buffered fp8 h

    v8i af[6];
    #pragma unroll
    for (int tg = 0; tg < 2; tg++)
        #pragma unroll
        for (int g = 0; g < 3; g++)
            af[tg * 3 + g] = *(const v8i*)(Whh + (long)(wid * 96 + tg * 48 + g * 16 + m) * HN + q * 32);

    const int tgl  = (m >> 2) & 1;
    const int rsel = m & 3;
    const int il   = wid * 32 + tgl * 16 + q * 4 + rsel;   // this lane's h index
    const int il3  = il * 3;
    const float bhr = Bhh[il], bhz = Bhh[HN + il], bhn = Bhh[2 * HN + il];

    if (tid < HN){ hst[0][tid] = 0; hst[1][tid] = 0; }

    const float* ga = gx + il3;
    float cr0 = ga[0], cz0 = ga[1], cn0 = ga[2];
    const float* gb = gx + G3 + il3;
    float cr1 = gb[0], cz1 = gb[1], cn1 = gb[2];

    __syncthreads();

    float h = 0.f;
    const f32x4 zf = {0.f, 0.f, 0.f, 0.f};

#define GRU_STEP(T, CR, CZ, CN, WB, RB)                                               \
    {                                                                                 \
        v8i bfrag = *(const v8i*)(&hst[RB][q * 32]);                                  \
        f32x4 a0 = __builtin_amdgcn_mfma_scale_f32_16x16x128_f8f6f4(af[0], bfrag, zf, 0, 0, 0, 127, 0, 127); \
        f32x4 a1 = __builtin_amdgcn_mfma_scale_f32_16x16x128_f8f6f4(af[1], bfrag, zf, 0, 0, 0, 127, 0, 127); \
        f32x4 a2 = __builtin_amdgcn_mfma_scale_f32_16x16x128_f8f6f4(af[2], bfrag, zf, 0, 0, 0, 127, 0, 127); \
        f32x4 a3 = __builtin_amdgcn_mfma_scale_f32_16x16x128_f8f6f4(af[3], bfrag, zf, 0, 0, 0, 127, 0, 127); \
        f32x4 a4 = __builtin_amdgcn_mfma_scale_f32_16x16x128_f8f6f4(af[4], bfrag, zf, 0, 0, 0, 127, 0, 127); \
        f32x4 a5 = __builtin_amdgcn_mfma_scale_f32_16x16x128_f8f6f4(af[5], bfrag, zf, 0, 0, 0, 127, 0, 127); \
        float ghr = sel4(tgl ? a3 : a0, rsel);                                        \
        float ghz = sel4(tgl ? a4 : a1, rsel);                                        \
        float ghn = sel4(tgl ? a5 : a2, rsel);                                        \
        float rg = sigm_f(CR + ghr + bhr);                                            \
        float zg = sigm_f(CZ + ghz + bhz);                                            \
        float ng = tanh_f(CN + rg * (ghn + bhn));                                     \
        h = (1.f - zg) * ng + zg * h;                                                 \
        if (m < 8){                                                                   \
            int pk = __builtin_amdgcn_cvt_pk_fp8_f32(h, h, 0, false);                 \
            hst[WB][il] = (u8)(pk & 0xFF);                                            \
        }                                                                             \
        int tp = ((T) + 2 < SEQL) ? (T) + 2 : SEQL - 1;                               \
        const float* gp = gx + (long)tp * G3 + il3;                                   \
        CR = gp[0]; CZ = gp[1]; CN = gp[2];                                           \
        asm volatile("s_waitcnt lgkmcnt(0)" ::: "memory");                            \
        __builtin_amdgcn_s_barrier();                                                 \
        asm volatile("" ::: "memory");                                                \
    }

    for (int t = 0; t < SEQL; t += 2){
        GRU_STEP(t,     cr0, cz0, cn0, 0, 1);
        GRU_STEP(t + 1, cr1, cz1, cn1, 1, 0);
    }
#undef GRU_STEP

    if (m < 8) Hout[s * HN + il] = h;
}

// ---------------- head: fc1+relu, fc2, log_softmax -> 3 fp32
__global__ __launch_bounds__(256) void final_k(const float* __restrict__ Hout,
                                               const float* __restrict__ fc1w, const float* __restrict__ fc1b,
                                               const float* __restrict__ fc2w, const float* __restrict__ fc2b,
                                               float* __restrict__ out)
{
    __shared__ float hb[256];
    __shared__ float r1[256];
    __shared__ float lg[3];
    int tid = threadIdx.x;
    hb[tid] = Hout[tid];
    __syncthreads();
    float a = 0.f;
    for (int k2 = 0; k2 < 256; k2++) a += hb[k2] * fc1w[tid * 256 + k2];
    a += fc1b[tid];
    r1[tid] = fmaxf(a, 0.f);
    __syncthreads();
    if (tid < 3){
        float v = 0.f;
        for (int k2 = 0; k2 < 256; k2++) v += r1[k2] * fc2w[tid * 256 + k2];
        lg[tid] = v + fc2b[tid];
    }
    __syncthreads();
    if (tid == 0){
        float mx = fmaxf(lg[0], fmaxf(lg[1], lg[2]));
        float se = __expf(lg[0] - mx) + __expf(lg[1] - mx) + __expf(lg[2] - mx);
        float ls = mx + logf(se);
        out[0] = lg[0] - ls;
        out[1] = lg[1] - ls;
        out[2] = lg[2] - ls;
    }
}

extern "C" void kernel_launch(void* const* d_in, const int* in_sizes, int n_in,
                              void* d_out, int out_size, void* d_ws, size_t ws_size,
                              hipStream_t stream)
{
    (void)in_sizes; (void)n_in; (void)out_size; (void)ws_size;
    const float* x1     = (const float*)d_in[0];
    const float* x2     = (const float*)d_in[1];
    const float* q_w    = (const float*)d_in[2],  *q_b   = (const float*)d_in[3];
    const float* k_w    = (const float*)d_in[4],  *k_b   = (const float*)d_in[5];
    const float* v_w    = (const float*)d_in[6],  *v_b   = (const float*)d_in[7];
    const float* aln_g  = (const float*)d_in[8],  *aln_b = (const float*)d_in[9];
    const float* w_w    = (const float*)d_in[10], *w_b   = (const float*)d_in[11];
    const float* mln_g  = (const float*)d_in[12], *mln_b = (const float*)d_in[13];
    const float* g1_wih = (const float*)d_in[14], *g1_whh = (const float*)d_in[15];
    const float* g1_bih = (const float*)d_in[16], *g1_bhh = (const float*)d_in[17];
    const float* g2_wih = (const float*)d_in[18], *g2_whh = (const float*)d_in[19];
    const float* g2_bih = (const float*)d_in[20], *g2_bhh = (const float*)d_in[21];
    const float* fc1w   = (const float*)d_in[22], *fc1b  = (const float*)d_in[23];
    const float* fc2w   = (const float*)d_in[24], *fc2b  = (const float*)d_in[25];

    char* wsp = (char*)d_ws;
    auto alloc = [&](size_t bytes) -> char* {
        char* p = wsp; wsp += (bytes + 255) & ~(size_t)255; return p;
    };
    float* XF   = (float*)alloc(2L * SEQL * DP * 4);   // fp32 stack input (residual for aln)
    u16*   CUR  = (u16*)  alloc(2L * SEQL * DP * 2);   // bf16 stack input (MFMA operand)
    u16*   Hb   = (u16*)  alloc(2L * SEQL * DP * 2);   // LN1 output bf16
    u16*   Wpk  = (u16*)  alloc(4L * DP * DP * 2);     // q,k,v,w packed bf16 [320][320]
    u16*   GWpk = (u16*)  alloc(2L * G3 * DP * 2);     // g{1,2}_wih packed bf16 [384][320]
    u8*    Whh8 = (u8*)   alloc(2L * G3 * HN);         // g{1,2}_whh fp8, gate-permuted rows
    float* Hout = (float*)alloc(2L * HN * 4);
    float* Lp   = (float*)alloc((long)JC * 2 * SEQL * 4);
    // union1: {QK 2 slices + VT} vs GX (permuted gate-triple layout)
    size_t u1 = (2L * 2 * SEQL * DP + 2L * DP * SEQL) * 2;
    size_t u1b = 2L * SEQL * G3 * 4;
    u16*   QKV  = (u16*)  alloc(u1 > u1b ? u1 : u1b);
    u16*   VT   = QKV + 2L * 2 * SEQL * DP;
    float* GX   = (float*)QKV;
    // union2: Onum (flash numerator partials, bf16)
    u16*   Onum = (u16*)  alloc((long)JC * 2 * SEQL * DP * 2);

    // prep (4 dispatches)
    pad_x2<<<dim3(256, 2), 256, 0, stream>>>(x1, x2, XF, CUR);
    cvt_pad_w4<<<dim3(128, 4), 256, 0, stream>>>(q_w, k_w, v_w, w_w, Wpk);
    cvt_pad_g2<<<dim3(128, 2), 256, 0, stream>>>(g1_wih, g2_wih, GWpk);
    cvt_whh2<<<dim3(192, 2), 256, 0, stream>>>(g1_whh, g2_whh, Whh8);

    for (int st = 0; st < 3; ++st){
        // Q,K -> QKV slices 0,1 ; V -> transposed at slice 2 (VT)
        gemm_k<NQT, 3, false><<<dim3(SEQL / 64, 3, 2), 256, 0, stream>>>(
            CUR, Wpk, q_b, k_b, v_b, VECT, QKV);
        flash_k<<<dim3(256), 256, 0, stream>>>(QKV, QKV + 2L*SEQL*DP, VT, Onum, Lp);
        lncomb_k<<<dim3(2 * SEQL / 4), 256, 0, stream>>>(Onum, Lp, XF, aln_g, aln_b, Hb);
        // fused: W-proj + residual(x) + LN2 -> CUR (bf16) + XF (fp32)
        gemmln_k<<<dim3(SEQL / 64, 1, 2), 256, 0, stream>>>(
            Hb, Wpk + 3L * DP * DP, w_b, x1, x2, mln_g, mln_b, CUR, XF);
    }

    // GRU input projections, gate-permuted output (weight/bias per seq) -> GX
    gemm_k<24, 4, true><<<dim3(SEQL / 64, 1, 2), 256, 0, stream>>>(
        CUR, GWpk, g1_bih, g2_bih, nullptr, G3, GX);
    gru_k<<<dim3(2), 256, 0, stream>>>(GX, Whh8, g1_bhh, g2_bhh, Hout);
    final_k<<<dim3(1), 256, 0, stream>>>(Hout, fc1w, fc1b, fc2w, fc2b, (float*)d_out);
}

// Round 12
// 2003.925 us; speedup vs baseline: 2.1021x; 1.0108x over previous
//
#include <hip/hip_runtime.h>
#include <hip/hip_bf16.h>

// Problem constants
#define SEQL 4096
#define VECT 300
#define DP   320     // padded feature dim (k-dim), 10 chunks of 32
#define NQT  20      // n-tiles (320 cols) for projection GEMMs
#define HN   128
#define G3   384     // 3*H
#define JC   4       // flash j-chunks (split-K over key dim)
#define KROW 328     // LDS K-tile row stride (u16)
#define VROW 40      // LDS VT-tile row stride (u16)
#define PROW 40      // pbuf row stride

typedef unsigned short u16;
typedef unsigned char  u8;
typedef __attribute__((ext_vector_type(8))) short bf16x8;  // 8 bf16 = 4 VGPRs
typedef __attribute__((ext_vector_type(4))) float f32x4;
typedef __attribute__((ext_vector_type(4))) unsigned int u32x4;
typedef __attribute__((ext_vector_type(8))) int   v8i;     // 8 dwords (fp8 x32)

#define MFMA(a,b,c) __builtin_amdgcn_mfma_f32_16x16x32_bf16(a,b,c,0,0,0)
// Verified layouts (learn_hip m89/m91/m120):
//   A[m][k]: m=lane&15, k=(lane>>4)*8+j
//   B[k][n]: n=lane&15, k=(lane>>4)*8+j
//   C/D[row][col]: col=lane&15, row=(lane>>4)*4+reg

#define L2E 1.44269504088896f

#define RAW_BAR() do {                                          \
    asm volatile("s_waitcnt lgkmcnt(0)" ::: "memory");          \
    __builtin_amdgcn_s_barrier();                               \
    asm volatile("" ::: "memory");                              \
} while (0)

__device__ __forceinline__ float bf2f(u16 v){
    union { unsigned u; float f; } t; t.u = ((unsigned)v) << 16; return t.f;
}
__device__ __forceinline__ u16 f2bf(float f){
    union { float f; unsigned u; } t; t.f = f;
    return (u16)((t.u + 0x7FFFu + ((t.u >> 16) & 1u)) >> 16);
}
__device__ __forceinline__ float sigm_f(float x){
    return __builtin_amdgcn_rcpf(1.f + __builtin_amdgcn_exp2f(-L2E * x));
}
__device__ __forceinline__ float tanh_f(float x){
    return fmaf(2.f, __builtin_amdgcn_rcpf(1.f + __builtin_amdgcn_exp2f(-2.f * L2E * x)), -1.f);
}
__device__ __forceinline__ float sel4(f32x4 v, int r){
    float a = (r & 1) ? v.y : v.x;
    float b = (r & 1) ? v.w : v.z;
    return (r & 2) ? b : a;
}

// ---------------- fused prep: x pad (y selects seq)
__global__ __launch_bounds__(256) void pad_x2(const float* __restrict__ x1, const float* __restrict__ x2,
                                              float* __restrict__ xf, u16* __restrict__ cur)
{
    int s = blockIdx.y;
    const float* src = s ? x2 : x1;
    float* xfo = xf + (long)s * SEQL * DP;
    u16*  cro = cur + (long)s * SEQL * DP;
    int n = SEQL * DP;
    for (int i = blockIdx.x * blockDim.x + threadIdx.x; i < n; i += gridDim.x * blockDim.x){
        int r = i / DP, c = i - r * DP;
        float v = (c < VECT) ? src[r * VECT + c] : 0.f;
        xfo[i] = v;
        cro[i] = f2bf(v);
    }
}

// ---------------- fused prep: 4 attention weights -> Wpk (y selects which)
__global__ __launch_bounds__(256) void cvt_pad_w4(const float* __restrict__ w0, const float* __restrict__ w1,
                                                  const float* __restrict__ w2, const float* __restrict__ w3,
                                                  u16* __restrict__ Wpk)
{
    int sl = blockIdx.y;
    const float* src = (sl == 0) ? w0 : (sl == 1) ? w1 : (sl == 2) ? w2 : w3;
    u16* dst = Wpk + (long)sl * DP * DP;
    int n = DP * DP;
    for (int i = blockIdx.x * blockDim.x + threadIdx.x; i < n; i += gridDim.x * blockDim.x){
        int r = i / DP, c = i - r * DP;
        float v = (r < VECT && c < VECT) ? src[r * VECT + c] : 0.f;
        dst[i] = f2bf(v);
    }
}

// ---------------- fused prep: 2 GRU input weights -> GWpk (y selects)
__global__ __launch_bounds__(256) void cvt_pad_g2(const float* __restrict__ w0, const float* __restrict__ w1,
                                                  u16* __restrict__ GWpk)
{
    int s = blockIdx.y;
    const float* src = s ? w1 : w0;
    u16* dst = GWpk + (long)s * G3 * DP;
    int n = G3 * DP;
    for (int i = blockIdx.x * blockDim.x + threadIdx.x; i < n; i += gridDim.x * blockDim.x){
        int r = i / DP, c = i - r * DP;
        float v = (c < VECT) ? src[r * VECT + c] : 0.f;
        dst[i] = f2bf(v);
    }
}

// ---------------- fused prep: Whh fp32 [384][128] -> fp8, gate-permuted rows (y selects seq)
// prow = w*96 + tg*48 + g*16 + rr  <->  orig row g*128 + (w*32 + tg*16 + rr)
__global__ __launch_bounds__(256) void cvt_whh2(const float* __restrict__ w0, const float* __restrict__ w1,
                                                u8* __restrict__ dst0)
{
    int s = blockIdx.y;
    const float* src = s ? w1 : w0;
    u8* dst = dst0 + (long)s * G3 * HN;
    int idx = blockIdx.x * 256 + threadIdx.x;
    if (idx >= G3 * HN) return;
    int prow = idx >> 7, col = idx & 127;
    int w  = prow / 96, rem = prow - w * 96;
    int tg = rem / 48;  rem -= tg * 48;
    int g  = rem >> 4;  int rr = rem & 15;
    int orow = g * 128 + w * 32 + tg * 16 + rr;
    int pk = __builtin_amdgcn_cvt_pk_fp8_f32(src[orow * HN + col], 0.f, 0, false);
    dst[idx] = (u8)(pk & 0xFF);
}

// ---------------- GEMM: Y[s][i][col] = sum_d A[s][i][d] * W[wsel][col][d] + bias[col]
// 256 thr = 4 waves; wave handles 16 rows; WG = 64 rows.
// OM: 3 = QKV fused (slices 0,1 row-major bf16, slice 2 transposed);
//     4 = fp32 with GRU gate-permuted columns: col = g*128+i -> i*3+g
template<int NT, int OM, bool WPERSEQ>
__global__ __launch_bounds__(256) void gemm_k(
    const u16* __restrict__ A, const u16* __restrict__ Wp,
    const float* __restrict__ b0, const float* __restrict__ b1, const float* __restrict__ b2,
    int nb, void* __restrict__ Out)
{
    const int lane = threadIdx.x & 63;
    const int wid  = threadIdx.x >> 6;
    const int s    = blockIdx.z;
    const int sl   = blockIdx.y;
    const int wsel = WPERSEQ ? s : sl;
    const int row0 = blockIdx.x * 64 + wid * 16;
    const int m    = lane & 15;
    const int q    = lane >> 4;

    const u16* Arow = A + ((long)s * SEQL + row0) * DP;
    const u16* W    = Wp + (long)wsel * (NT * 16) * DP;

    f32x4 zf = {0.f, 0.f, 0.f, 0.f};
    f32x4 acc[NT];
    #pragma unroll
    for (int n = 0; n < NT; n++) acc[n] = zf;

    for (int c = 0; c < DP / 32; ++c){
        const int koff = c * 32 + q * 8;
        bf16x8 a0 = *(const bf16x8*)(Arow + m * DP + koff);
        #pragma unroll
        for (int n = 0; n < NT; n++){
            bf16x8 b = *(const bf16x8*)(W + (n * 16 + m) * DP + koff);
            acc[n] = MFMA(a0, b, acc[n]);
        }
    }

    const int bsel = WPERSEQ ? s : sl;
    const float* bp = (bsel == 0) ? b0 : ((bsel == 1) ? b1 : b2);
    const long SLC = 2L * SEQL * DP;  // per-slice stride in QKV buffer

    #pragma unroll
    for (int n = 0; n < NT; n++){
        int col = n * 16 + m;
        float bv = (col < nb) ? bp[col] : 0.f;
        #pragma unroll
        for (int r = 0; r < 4; r++){
            long row = row0 + q * 4 + r;
            float v = acc[n][r] + bv;
            if (OM == 4){
                int g = col >> 7, i2 = col & 127;
                long off = ((long)s * SEQL + row) * (long)(NT * 16) + (i2 * 3 + g);
                ((float*)Out)[off] = v;
            } else {  // OM == 3
                long off;
                if (sl < 2) off = ((long)(sl * 2 + s) * SEQL + row) * DP + col;
                else        off = 2 * SLC + ((long)s * DP + col) * SEQL + row;
                ((u16*)Out)[off] = f2bf(v);
            }
        }
    }
}

// ---------------- fused W-projection + residual + LayerNorm2:
// CUR/XF[row] = LN(Hb[row] @ W^T + w_b + x[row]) * g + b   (bf16 + fp32 outputs)
__global__ __launch_bounds__(256) void gemmln_k(
    const u16* __restrict__ A, const u16* __restrict__ Wp, const float* __restrict__ bias,
    const float* __restrict__ res0, const float* __restrict__ res1,
    const float* __restrict__ g, const float* __restrict__ b,
    u16* __restrict__ OutB, float* __restrict__ OutF)
{
    const int lane = threadIdx.x & 63;
    const int wid  = threadIdx.x >> 6;
    const int s    = blockIdx.z;
    const int row0 = blockIdx.x * 64 + wid * 16;
    const int m    = lane & 15;
    const int q    = lane >> 4;

    const u16* Arow = A + ((long)s * SEQL + row0) * DP;
    const float* res = s ? res1 : res0;

    f32x4 zf = {0.f, 0.f, 0.f, 0.f};
    f32x4 acc[NQT];
    #pragma unroll
    for (int n = 0; n < NQT; n++) acc[n] = zf;

    for (int c = 0; c < DP / 32; ++c){
        const int koff = c * 32 + q * 8;
        bf16x8 a0 = *(const bf16x8*)(Arow + m * DP + koff);
        #pragma unroll
        for (int n = 0; n < NQT; n++){
            bf16x8 bb = *(const bf16x8*)(Wp + (n * 16 + m) * DP + koff);
            acc[n] = MFMA(a0, bb, acc[n]);
        }
    }

    float sum[4] = {0,0,0,0}, sq[4] = {0,0,0,0};
    #pragma unroll
    for (int n = 0; n < NQT; n++){
        int col = n * 16 + m;
        float bv = (col < VECT) ? bias[col] : 0.f;
        #pragma unroll
        for (int r = 0; r < 4; r++){
            long row = row0 + q * 4 + r;
            float rr = (col < VECT) ? res[row * VECT + col] : 0.f;
            float t = (col < VECT) ? (acc[n][r] + bv + rr) : 0.f;
            acc[n][r] = t;
            sum[r] += t; sq[r] += t * t;
        }
    }
    #pragma unroll
    for (int r = 0; r < 4; r++){
        float su = sum[r], sv = sq[r];
        su += __shfl_xor(su, 1); sv += __shfl_xor(sv, 1);
        su += __shfl_xor(su, 2); sv += __shfl_xor(sv, 2);
        su += __shfl_xor(su, 4); sv += __shfl_xor(sv, 4);
        su += __shfl_xor(su, 8); sv += __shfl_xor(sv, 8);
        sum[r] = su; sq[r] = sv;
    }
    float mean[4], rstd[4];
    #pragma unroll
    for (int r = 0; r < 4; r++){
        mean[r] = sum[r] / VECT;
        float var = sq[r] / VECT - mean[r] * mean[r];
        rstd[r] = rsqrtf(var + 1e-5f);
    }
    #pragma unroll
    for (int n = 0; n < NQT; n++){
        int col = n * 16 + m;
        float gv = (col < VECT) ? g[col] : 0.f;
        float bv = (col < VECT) ? b[col] : 0.f;
        #pragma unroll
        for (int r = 0; r < 4; r++){
            long row = (long)s * SEQL + row0 + q * 4 + r;
            float t = (col < VECT) ? ((acc[n][r] - mean[r]) * rstd[r] * gv + bv) : 0.f;
            OutB[row * DP + col] = f2bf(t);
            OutF[row * DP + col] = t;
        }
    }
}

// ---------------- flash attention chunk, LDS-tiled, 2 WGs/CU:
// WG covers 64 Q-rows (wave = 1 m-tile); K/VT tiles staged once per WG into LDS
// (52 KB/WG -> two WGs co-resident per CU so barrier stalls overlap with the
// other WG's MFMA bursts). Grid 512 = 64 xi * 8 combos, combo = bid&7 -> (jc,s).
__global__ __launch_bounds__(256, 2) void flash_k(
    const u16* __restrict__ Q, const u16* __restrict__ K, const u16* __restrict__ VT,
    u16* __restrict__ Onum, float* __restrict__ Lp)
{
    const int tid  = threadIdx.x;
    const int lane = tid & 63;
    const int wid  = tid >> 6;
    const int bid  = blockIdx.x;
    const int s    = bid & 1;
    const int jc   = (bid >> 1) & 3;
    const int xi   = bid >> 3;
    const int row0 = xi * 64 + wid * 16;
    const int m = lane & 15, q = lane >> 4;

    __shared__ __align__(16) u16 Kt[32 * KROW];        // 21.0 KB
    __shared__ __align__(16) u16 Vt[DP * VROW];        // 25.6 KB
    __shared__ __align__(16) u16 pb[4][16 * PROW];     // 5.1 KB

    const u16* Qb = Q  + ((long)s * SEQL + row0) * DP;
    const u16* Kc = K  + (long)s * SEQL * DP + (long)jc * 1024 * DP;
    const u16* Vc = VT + (long)s * DP * SEQL + jc * 1024;

    bf16x8 qf[10];
    #pragma unroll
    for (int c = 0; c < 10; c++)
        qf[c] = *(const bf16x8*)(Qb + m * DP + c * 32 + q * 8);

    int skoff[5], wkoff[5], svoff[5], wvoff[5];
    #pragma unroll
    for (int it = 0; it < 5; it++){
        int f  = (it * 256 + tid) * 8;
        int rk = f / 320, ck = f - rk * 320;
        skoff[it] = f;
        wkoff[it] = rk * KROW + ck;
        int rv = f >> 5, cv = f & 31;
        svoff[it] = rv * SEQL + cv;
        wvoff[it] = rv * VROW + cv;
    }

    f32x4 zf = {0.f, 0.f, 0.f, 0.f};
    f32x4 oacc[NQT];
    #pragma unroll
    for (int n = 0; n < NQT; n++) oacc[n] = zf;
    float lacc[4] = {0,0,0,0};

    const float K2 = 0.057735026918962576f * L2E;
    const float MB = -16.f * L2E;

    u32x4 kreg[5], vreg[5];
    #pragma unroll
    for (int it = 0; it < 5; it++){
        kreg[it] = *(const u32x4*)(Kc + skoff[it]);
        vreg[it] = *(const u32x4*)(Vc + svoff[it]);
    }
    #pragma unroll
    for (int it = 0; it < 5; it++){
        *(u32x4*)(&Kt[wkoff[it]]) = kreg[it];
        *(u32x4*)(&Vt[wvoff[it]]) = vreg[it];
    }
    RAW_BAR();

    u16* pbw = &pb[wid][0];

    for (int j = 0; j < 32; ++j){
        if (j + 1 < 32){
            const u16* Kj = Kc + (j + 1) * 32 * DP;
            const u16* Vj = Vc + (j + 1) * 32;
            #pragma unroll
            for (int it = 0; it < 5; it++){
                kreg[it] = *(const u32x4*)(Kj + skoff[it]);
                vreg[it] = *(const u32x4*)(Vj + svoff[it]);
            }
        }
        f32x4 sA = zf, sB = zf;
        #pragma unroll
        for (int c = 0; c < 10; c++){
            bf16x8 kA = *(const bf16x8*)(&Kt[(m     ) * KROW + c * 32 + q * 8]);
            bf16x8 kB = *(const bf16x8*)(&Kt[(m + 16) * KROW + c * 32 + q * 8]);
            sA = MFMA(qf[c], kA, sA);
            sB = MFMA(qf[c], kB, sB);
        }
        #pragma unroll
        for (int r = 0; r < 4; r++){
            float a = __builtin_amdgcn_exp2f(fmaf(sA[r], K2, MB));
            float b = __builtin_amdgcn_exp2f(fmaf(sB[r], K2, MB));
            lacc[r] += a + b;
            pbw[(q * 4 + r) * PROW +      m] = f2bf(a);
            pbw[(q * 4 + r) * PROW + 16 + m] = f2bf(b);
        }
        bf16x8 pf = *(const bf16x8*)(&pbw[m * PROW + q * 8]);
        #pragma unroll
        for (int n = 0; n < NQT; n++){
            bf16x8 vb = *(const bf16x8*)(&Vt[(n * 16 + m) * VROW + q * 8]);
            oacc[n] = MFMA(pf, vb, oacc[n]);
        }
        RAW_BAR();                    // all waves done reading Kt/Vt for j
        if (j + 1 < 32){
            #pragma unroll
            for (int it = 0; it < 5; it++){
                *(u32x4*)(&Kt[wkoff[it]]) = kreg[it];
                *(u32x4*)(&Vt[wvoff[it]]) = vreg[it];
            }
        }
        RAW_BAR();                    // tiles for j+1 published
    }

    #pragma unroll
    for (int r = 0; r < 4; r++){
        float t0 = lacc[r];
        t0 += __shfl_xor(t0, 1); t0 += __shfl_xor(t0, 2);
        t0 += __shfl_xor(t0, 4); t0 += __shfl_xor(t0, 8);
        lacc[r] = t0;
    }
    const long grow0 = (long)s * SEQL + row0;
    if (m == 0){
        #pragma unroll
        for (int r = 0; r < 4; r++)
            Lp[(long)jc * 2 * SEQL + grow0 + q * 4 + r] = lacc[r];
    }
    u16* Ob = Onum + ((long)jc * 2 * SEQL + grow0) * DP;
    #pragma unroll
    for (int n = 0; n < NQT; n++)
        #pragma unroll
        for (int r = 0; r < 4; r++)
            Ob[(long)(q * 4 + r) * DP + n * 16 + m] = f2bf(oacc[n][r]);
}

// ---------------- combine chunks + LayerNorm1: out = LN(sum(Onum)/sum(l) + XF) * g + b
__global__ __launch_bounds__(256) void lncomb_k(const u16* __restrict__ Onum, const float* __restrict__ Lp,
                                                const float* __restrict__ XF,
                                                const float* __restrict__ g, const float* __restrict__ b,
                                                u16* __restrict__ OutB)
{
    long row = (long)((blockIdx.x * blockDim.x + threadIdx.x) >> 6);
    int lane = threadIdx.x & 63;
    if (row >= 2L * SEQL) return;
    float l = 0.f;
    #pragma unroll
    for (int jc = 0; jc < JC; jc++) l += Lp[(long)jc * 2 * SEQL + row];
    float inv = 1.f / l;
    const float* xr = XF + row * DP;
    float v[5], sum = 0.f, sq = 0.f;
    #pragma unroll
    for (int i = 0; i < 5; i++){
        int c = lane + i * 64;
        float o = 0.f;
        #pragma unroll
        for (int jc = 0; jc < JC; jc++)
            o += bf2f(Onum[((long)jc * 2 * SEQL + row) * DP + c]);
        float t = (c < VECT) ? (o * inv + xr[c]) : 0.f;
        v[i] = t; sum += t; sq += t * t;
    }
    #pragma unroll
    for (int o = 1; o < 64; o <<= 1){ sum += __shfl_xor(sum, o); sq += __shfl_xor(sq, o); }
    float mean = sum / VECT;
    float var  = sq / VECT - mean * mean;
    float rstd = rsqrtf(var + 1e-5f);
    #pragma unroll
    for (int i = 0; i < 5; i++){
        int c = lane + i * 64;
        float t = (c < VECT) ? ((v[i] - mean) * rstd * g[c] + b[c]) : 0.f;
        OutB[row * DP + c] = f2bf(t);
    }
}

// ---------------- GRU (r10 config — measured win): 1 WG/seq, 4 waves, ONE raw barrier/step,
// gates in-register via gate-permuted fp8 K=128 MFMA; 128 B double-buffered h exchange.
__global__ __launch_bounds__(256, 1) void gru_k(
    const float* __restrict__ GXP,                         // [2][SEQL][384] fp32, permuted i*3+g
    const u8* __restrict__ Whh8p,                          // [2][384][128] fp8, permuted rows
    const float* __restrict__ Bhh1, const float* __restrict__ Bhh2,
    float* __restrict__ Hout)                              // [2][128] fp32
{
    const int s = blockIdx.x;
    const int tid = threadIdx.x;
    const int lane = tid & 63;
    const int wid  = tid >> 6;
    const int m = lane & 15, q = lane >> 4;
    const u8* Whh = Whh8p + (long)s * G3 * HN;
    const float* Bhh = s ? Bhh2 : Bhh1;
    const float* gx = GXP + (long)s * SEQL * G3;

    __shared__ __align__(8) u8 hst[2][HN];     // double-buffered fp8 h

    v8i af[6];
    #pragma unroll
    for (int tg = 0; tg < 2; tg++)
        #pragma unroll
        for (int g = 0; g < 3; g++)
            af[tg * 3 + g] = *(const v8i*)(Whh + (long)(wid * 96 + tg * 48 + g * 16 + m) * HN + q * 32);

    const int tgl  = (m >> 2) & 1;
    const int rsel = m & 3;
    const int il   = wid * 32 + tgl * 16 + q * 4 + rsel;   // this lane's h index
    const int il3  = il * 3;
    const float bhr = Bhh[il], bhz = Bhh[HN + il], bhn = Bhh[2 * HN + il];

    if (tid < HN){ hst[0][tid] = 0; hst[1][tid] = 0; }

    const float* ga = gx + il3;
    float cr0 = ga[0], cz0 = ga[1], cn0 = ga[2];
    const float* gb = gx + G3 + il3;
    float cr1 = gb[0], cz1 = gb[1], cn1 = gb[2];

    __syncthreads();

    float h = 0.f;
    const f32x4 zf = {0.f, 0.f, 0.f, 0.f};

#define GRU_STEP(T, CR, CZ, CN, WB, RB)                                               \
    {                                                                                 \
        v8i bfrag = *(const v8i*)(&hst[RB][q * 32]);                                  \
        f32x4 a0 = __builtin_amdgcn_mfma_scale_f32_16x16x128_f8f6f4(af[0], bfrag, zf, 0, 0, 0, 127, 0, 127); \
        f32x4 a1 = __builtin_amdgcn_mfma_scale_f32_16x16x128_f8f6f4(af[1], bfrag, zf, 0, 0, 0, 127, 0, 127); \
        f32x4 a2 = __builtin_amdgcn_mfma_scale_f32_16x16x128_f8f6f4(af[2], bfrag, zf, 0, 0, 0, 127, 0, 127); \
        f32x4 a3 = __builtin_amdgcn_mfma_scale_f32_16x16x128_f8f6f4(af[3], bfrag, zf, 0, 0, 0, 127, 0, 127); \
        f32x4 a4 = __builtin_amdgcn_mfma_scale_f32_16x16x128_f8f6f4(af[4], bfrag, zf, 0, 0, 0, 127, 0, 127); \
        f32x4 a5 = __builtin_amdgcn_mfma_scale_f32_16x16x128_f8f6f4(af[5], bfrag, zf, 0, 0, 0, 127, 0, 127); \
        float ghr = sel4(tgl ? a3 : a0, rsel);                                        \
        float ghz = sel4(tgl ? a4 : a1, rsel);                                        \
        float ghn = sel4(tgl ? a5 : a2, rsel);                                        \
        float rg = sigm_f(CR + ghr + bhr);                                            \
        float zg = sigm_f(CZ + ghz + bhz);                                            \
        float ng = tanh_f(CN + rg * (ghn + bhn));                                     \
        h = (1.f - zg) * ng + zg * h;                                                 \
        if (m < 8){                                                                   \
            int pk = __builtin_amdgcn_cvt_pk_fp8_f32(h, h, 0, false);                 \
            hst[WB][il] = (u8)(pk & 0xFF);                                            \
        }                                                                             \
        int tp = ((T) + 2 < SEQL) ? (T) + 2 : SEQL - 1;                               \
        const float* gp = gx + (long)tp * G3 + il3;                                   \
        CR = gp[0]; CZ = gp[1]; CN = gp[2];                                           \
        asm volatile("s_waitcnt lgkmcnt(0)" ::: "memory");                            \
        __builtin_amdgcn_s_barrier();                                                 \
        asm volatile("" ::: "memory");                                                \
    }

    for (int t = 0; t < SEQL; t += 2){
        GRU_STEP(t,     cr0, cz0, cn0, 0, 1);
        GRU_STEP(t + 1, cr1, cz1, cn1, 1, 0);
    }
#undef GRU_STEP

    if (m < 8) Hout[s * HN + il] = h;
}

// ---------------- head: fc1+relu, fc2, log_softmax -> 3 fp32
__global__ __launch_bounds__(256) void final_k(const float* __restrict__ Hout,
                                               const float* __restrict__ fc1w, const float* __restrict__ fc1b,
                                               const float* __restrict__ fc2w, const float* __restrict__ fc2b,
                                               float* __restrict__ out)
{
    __shared__ float hb[256];
    __shared__ float r1[256];
    __shared__ float lg[3];
    int tid = threadIdx.x;
    hb[tid] = Hout[tid];
    __syncthreads();
    float a = 0.f;
    for (int k2 = 0; k2 < 256; k2++) a += hb[k2] * fc1w[tid * 256 + k2];
    a += fc1b[tid];
    r1[tid] = fmaxf(a, 0.f);
    __syncthreads();
    if (tid < 3){
        float v = 0.f;
        for (int k2 = 0; k2 < 256; k2++) v += r1[k2] * fc2w[tid * 256 + k2];
        lg[tid] = v + fc2b[tid];
    }
    __syncthreads();
    if (tid == 0){
        float mx = fmaxf(lg[0], fmaxf(lg[1], lg[2]));
        float se = __expf(lg[0] - mx) + __expf(lg[1] - mx) + __expf(lg[2] - mx);
        float ls = mx + logf(se);
        out[0] = lg[0] - ls;
        out[1] = lg[1] - ls;
        out[2] = lg[2] - ls;
    }
}

extern "C" void kernel_launch(void* const* d_in, const int* in_sizes, int n_in,
                              void* d_out, int out_size, void* d_ws, size_t ws_size,
                              hipStream_t stream)
{
    (void)in_sizes; (void)n_in; (void)out_size; (void)ws_size;
    const float* x1     = (const float*)d_in[0];
    const float* x2     = (const float*)d_in[1];
    const float* q_w    = (const float*)d_in[2],  *q_b   = (const float*)d_in[3];
    const float* k_w    = (const float*)d_in[4],  *k_b   = (const float*)d_in[5];
    const float* v_w    = (const float*)d_in[6],  *v_b   = (const float*)d_in[7];
    const float* aln_g  = (const float*)d_in[8],  *aln_b = (const float*)d_in[9];
    const float* w_w    = (const float*)d_in[10], *w_b   = (const float*)d_in[11];
    const float* mln_g  = (const float*)d_in[12], *mln_b = (const float*)d_in[13];
    const float* g1_wih = (const float*)d_in[14], *g1_whh = (const float*)d_in[15];
    const float* g1_bih = (const float*)d_in[16], *g1_bhh = (const float*)d_in[17];
    const float* g2_wih = (const float*)d_in[18], *g2_whh = (const float*)d_in[19];
    const float* g2_bih = (const float*)d_in[20], *g2_bhh = (const float*)d_in[21];
    const float* fc1w   = (const float*)d_in[22], *fc1b  = (const float*)d_in[23];
    const float* fc2w   = (const float*)d_in[24], *fc2b  = (const float*)d_in[25];

    char* wsp = (char*)d_ws;
    auto alloc = [&](size_t bytes) -> char* {
        char* p = wsp; wsp += (bytes + 255) & ~(size_t)255; return p;
    };
    float* XF   = (float*)alloc(2L * SEQL * DP * 4);   // fp32 stack input (residual for aln)
    u16*   CUR  = (u16*)  alloc(2L * SEQL * DP * 2);   // bf16 stack input (MFMA operand)
    u16*   Hb   = (u16*)  alloc(2L * SEQL * DP * 2);   // LN1 output bf16
    u16*   Wpk  = (u16*)  alloc(4L * DP * DP * 2);     // q,k,v,w packed bf16 [320][320]
    u16*   GWpk = (u16*)  alloc(2L * G3 * DP * 2);     // g{1,2}_wih packed bf16 [384][320]
    u8*    Whh8 = (u8*)   alloc(2L * G3 * HN);         // g{1,2}_whh fp8, gate-permuted rows
    float* Hout = (float*)alloc(2L * HN * 4);
    float* Lp   = (float*)alloc((long)JC * 2 * SEQL * 4);
    // union1: {QK 2 slices + VT} vs GX (permuted gate-triple layout)
    size_t u1 = (2L * 2 * SEQL * DP + 2L * DP * SEQL) * 2;
    size_t u1b = 2L * SEQL * G3 * 4;
    u16*   QKV  = (u16*)  alloc(u1 > u1b ? u1 : u1b);
    u16*   VT   = QKV + 2L * 2 * SEQL * DP;
    float* GX   = (float*)QKV;
    // union2: Onum (flash numerator partials, bf16)
    u16*   Onum = (u16*)  alloc((long)JC * 2 * SEQL * DP * 2);

    // prep (4 dispatches)
    pad_x2<<<dim3(256, 2), 256, 0, stream>>>(x1, x2, XF, CUR);
    cvt_pad_w4<<<dim3(128, 4), 256, 0, stream>>>(q_w, k_w, v_w, w_w, Wpk);
    cvt_pad_g2<<<dim3(128, 2), 256, 0, stream>>>(g1_wih, g2_wih, GWpk);
    cvt_whh2<<<dim3(192, 2), 256, 0, stream>>>(g1_whh, g2_whh, Whh8);

    for (int st = 0; st < 3; ++st){
        // Q,K -> QKV slices 0,1 ; V -> transposed at slice 2 (VT)
        gemm_k<NQT, 3, false><<<dim3(SEQL / 64, 3, 2), 256, 0, stream>>>(
            CUR, Wpk, q_b, k_b, v_b, VECT, QKV);
        flash_k<<<dim3(512), 256, 0, stream>>>(QKV, QKV + 2L*SEQL*DP, VT, Onum, Lp);
        lncomb_k<<<dim3(2 * SEQL / 4), 256, 0, stream>>>(Onum, Lp, XF, aln_g, aln_b, Hb);
        // fused: W-proj + residual(x) + LN2 -> CUR (bf16) + XF (fp32)
        gemmln_k<<<dim3(SEQL / 64, 1, 2), 256, 0, stream>>>(
            Hb, Wpk + 3L * DP * DP, w_b, x1, x2, mln_g, mln_b, CUR, XF);
    }

    // GRU input projections, gate-permuted output (weight/bias per seq) -> GX
    gemm_k<24, 4, true><<<dim3(SEQL / 64, 1, 2), 256, 0, stream>>>(
        CUR, GWpk, g1_bih, g2_bih, nullptr, G3, GX);
    gru_k<<<dim3(2), 256, 0, stream>>>(GX, Whh8, g1_bhh, g2_bhh, Hout);
    final_k<<<dim3(1), 256, 0, stream>>>(Hout, fc1w, fc1b, fc2w, fc2b, (float*)d_out);
}

// Round 13
// 2000.482 us; speedup vs baseline: 2.1057x; 1.0017x over previous
//
#include <hip/hip_runtime.h>
#include <hip/hip_bf16.h>

// Problem constants
#define SEQL 4096
#define VECT 300
#define DP   320     // padded feature dim (k-dim), 10 chunks of 32
#define NQT  20      // n-tiles (320 cols) for projection GEMMs
#define HN   128
#define G3   384     // 3*H
#define JC   4       // flash j-chunks (split-K over key dim)
#define KROW 328     // LDS K-tile row stride (u16)
#define VROW 40      // LDS VT-tile row stride (u16)
#define PROW 40      // pbuf row stride

typedef unsigned short u16;
typedef unsigned char  u8;
typedef __attribute__((ext_vector_type(8))) short bf16x8;  // 8 bf16 = 4 VGPRs
typedef __attribute__((ext_vector_type(4))) float f32x4;
typedef __attribute__((ext_vector_type(4))) unsigned int u32x4;
typedef __attribute__((ext_vector_type(8))) int   v8i;     // 8 dwords (fp8 x32)

#define MFMA(a,b,c) __builtin_amdgcn_mfma_f32_16x16x32_bf16(a,b,c,0,0,0)
// Verified layouts (learn_hip m89/m91/m120):
//   A[m][k]: m=lane&15, k=(lane>>4)*8+j
//   B[k][n]: n=lane&15, k=(lane>>4)*8+j
//   C/D[row][col]: col=lane&15, row=(lane>>4)*4+reg

#define L2E 1.44269504088896f

#define RAW_BAR() do {                                          \
    asm volatile("s_waitcnt lgkmcnt(0)" ::: "memory");          \
    __builtin_amdgcn_s_barrier();                               \
    asm volatile("" ::: "memory");                              \
} while (0)

__device__ __forceinline__ float bf2f(u16 v){
    union { unsigned u; float f; } t; t.u = ((unsigned)v) << 16; return t.f;
}
__device__ __forceinline__ u16 f2bf(float f){
    union { float f; unsigned u; } t; t.f = f;
    return (u16)((t.u + 0x7FFFu + ((t.u >> 16) & 1u)) >> 16);
}
__device__ __forceinline__ float sigm_f(float x){
    return __builtin_amdgcn_rcpf(1.f + __builtin_amdgcn_exp2f(-L2E * x));
}
__device__ __forceinline__ float tanh_f(float x){
    return fmaf(2.f, __builtin_amdgcn_rcpf(1.f + __builtin_amdgcn_exp2f(-2.f * L2E * x)), -1.f);
}
__device__ __forceinline__ float sel4(f32x4 v, int r){
    float a = (r & 1) ? v.y : v.x;
    float b = (r & 1) ? v.w : v.z;
    return (r & 2) ? b : a;
}

// ---------------- fused prep: x pad (y selects seq)
__global__ __launch_bounds__(256) void pad_x2(const float* __restrict__ x1, const float* __restrict__ x2,
                                              float* __restrict__ xf, u16* __restrict__ cur)
{
    int s = blockIdx.y;
    const float* src = s ? x2 : x1;
    float* xfo = xf + (long)s * SEQL * DP;
    u16*  cro = cur + (long)s * SEQL * DP;
    int n = SEQL * DP;
    for (int i = blockIdx.x * blockDim.x + threadIdx.x; i < n; i += gridDim.x * blockDim.x){
        int r = i / DP, c = i - r * DP;
        float v = (c < VECT) ? src[r * VECT + c] : 0.f;
        xfo[i] = v;
        cro[i] = f2bf(v);
    }
}

// ---------------- fused prep: 4 attention weights -> Wpk (y selects which)
__global__ __launch_bounds__(256) void cvt_pad_w4(const float* __restrict__ w0, const float* __restrict__ w1,
                                                  const float* __restrict__ w2, const float* __restrict__ w3,
                                                  u16* __restrict__ Wpk)
{
    int sl = blockIdx.y;
    const float* src = (sl == 0) ? w0 : (sl == 1) ? w1 : (sl == 2) ? w2 : w3;
    u16* dst = Wpk + (long)sl * DP * DP;
    int n = DP * DP;
    for (int i = blockIdx.x * blockDim.x + threadIdx.x; i < n; i += gridDim.x * blockDim.x){
        int r = i / DP, c = i - r * DP;
        float v = (r < VECT && c < VECT) ? src[r * VECT + c] : 0.f;
        dst[i] = f2bf(v);
    }
}

// ---------------- fused prep: 2 GRU input weights -> GWpk (y selects)
__global__ __launch_bounds__(256) void cvt_pad_g2(const float* __restrict__ w0, const float* __restrict__ w1,
                                                  u16* __restrict__ GWpk)
{
    int s = blockIdx.y;
    const float* src = s ? w1 : w0;
    u16* dst = GWpk + (long)s * G3 * DP;
    int n = G3 * DP;
    for (int i = blockIdx.x * blockDim.x + threadIdx.x; i < n; i += gridDim.x * blockDim.x){
        int r = i / DP, c = i - r * DP;
        float v = (c < VECT) ? src[r * VECT + c] : 0.f;
        dst[i] = f2bf(v);
    }
}

// ---------------- fused prep: Whh fp32 [384][128] -> fp8, 8-wave gate-permuted rows
// prow = w*48 + g*16 + rr  <->  orig row g*128 + (w*16 + rr)   (w = 0..7)
__global__ __launch_bounds__(256) void cvt_whh2(const float* __restrict__ w0, const float* __restrict__ w1,
                                                u8* __restrict__ dst0)
{
    int s = blockIdx.y;
    const float* src = s ? w1 : w0;
    u8* dst = dst0 + (long)s * G3 * HN;
    int idx = blockIdx.x * 256 + threadIdx.x;
    if (idx >= G3 * HN) return;
    int prow = idx >> 7, col = idx & 127;
    int w  = prow / 48, rem = prow - w * 48;
    int g  = rem >> 4;  int rr = rem & 15;
    int orow = g * 128 + w * 16 + rr;
    int pk = __builtin_amdgcn_cvt_pk_fp8_f32(src[orow * HN + col], 0.f, 0, false);
    dst[idx] = (u8)(pk & 0xFF);
}

// ---------------- GEMM: Y[s][i][col] = sum_d A[s][i][d] * W[wsel][col][d] + bias[col]
// 256 thr = 4 waves; wave handles 16 rows; WG = 64 rows.
// OM: 3 = QKV fused (slices 0,1 row-major bf16, slice 2 transposed);
//     4 = fp32 with GRU gate-permuted columns: col = g*128+i -> i*3+g
template<int NT, int OM, bool WPERSEQ>
__global__ __launch_bounds__(256) void gemm_k(
    const u16* __restrict__ A, const u16* __restrict__ Wp,
    const float* __restrict__ b0, const float* __restrict__ b1, const float* __restrict__ b2,
    int nb, void* __restrict__ Out)
{
    const int lane = threadIdx.x & 63;
    const int wid  = threadIdx.x >> 6;
    const int s    = blockIdx.z;
    const int sl   = blockIdx.y;
    const int wsel = WPERSEQ ? s : sl;
    const int row0 = blockIdx.x * 64 + wid * 16;
    const int m    = lane & 15;
    const int q    = lane >> 4;

    const u16* Arow = A + ((long)s * SEQL + row0) * DP;
    const u16* W    = Wp + (long)wsel * (NT * 16) * DP;

    f32x4 zf = {0.f, 0.f, 0.f, 0.f};
    f32x4 acc[NT];
    #pragma unroll
    for (int n = 0; n < NT; n++) acc[n] = zf;

    for (int c = 0; c < DP / 32; ++c){
        const int koff = c * 32 + q * 8;
        bf16x8 a0 = *(const bf16x8*)(Arow + m * DP + koff);
        #pragma unroll
        for (int n = 0; n < NT; n++){
            bf16x8 b = *(const bf16x8*)(W + (n * 16 + m) * DP + koff);
            acc[n] = MFMA(a0, b, acc[n]);
        }
    }

    const int bsel = WPERSEQ ? s : sl;
    const float* bp = (bsel == 0) ? b0 : ((bsel == 1) ? b1 : b2);
    const long SLC = 2L * SEQL * DP;  // per-slice stride in QKV buffer

    #pragma unroll
    for (int n = 0; n < NT; n++){
        int col = n * 16 + m;
        float bv = (col < nb) ? bp[col] : 0.f;
        #pragma unroll
        for (int r = 0; r < 4; r++){
            long row = row0 + q * 4 + r;
            float v = acc[n][r] + bv;
            if (OM == 4){
                int g = col >> 7, i2 = col & 127;
                long off = ((long)s * SEQL + row) * (long)(NT * 16) + (i2 * 3 + g);
                ((float*)Out)[off] = v;
            } else {  // OM == 3
                long off;
                if (sl < 2) off = ((long)(sl * 2 + s) * SEQL + row) * DP + col;
                else        off = 2 * SLC + ((long)s * DP + col) * SEQL + row;
                ((u16*)Out)[off] = f2bf(v);
            }
        }
    }
}

// ---------------- fused W-projection + residual + LayerNorm2:
// CUR/XF[row] = LN(Hb[row] @ W^T + w_b + x[row]) * g + b   (bf16 + fp32 outputs)
__global__ __launch_bounds__(256) void gemmln_k(
    const u16* __restrict__ A, const u16* __restrict__ Wp, const float* __restrict__ bias,
    const float* __restrict__ res0, const float* __restrict__ res1,
    const float* __restrict__ g, const float* __restrict__ b,
    u16* __restrict__ OutB, float* __restrict__ OutF)
{
    const int lane = threadIdx.x & 63;
    const int wid  = threadIdx.x >> 6;
    const int s    = blockIdx.z;
    const int row0 = blockIdx.x * 64 + wid * 16;
    const int m    = lane & 15;
    const int q    = lane >> 4;

    const u16* Arow = A + ((long)s * SEQL + row0) * DP;
    const float* res = s ? res1 : res0;

    f32x4 zf = {0.f, 0.f, 0.f, 0.f};
    f32x4 acc[NQT];
    #pragma unroll
    for (int n = 0; n < NQT; n++) acc[n] = zf;

    for (int c = 0; c < DP / 32; ++c){
        const int koff = c * 32 + q * 8;
        bf16x8 a0 = *(const bf16x8*)(Arow + m * DP + koff);
        #pragma unroll
        for (int n = 0; n < NQT; n++){
            bf16x8 bb = *(const bf16x8*)(Wp + (n * 16 + m) * DP + koff);
            acc[n] = MFMA(a0, bb, acc[n]);
        }
    }

    float sum[4] = {0,0,0,0}, sq[4] = {0,0,0,0};
    #pragma unroll
    for (int n = 0; n < NQT; n++){
        int col = n * 16 + m;
        float bv = (col < VECT) ? bias[col] : 0.f;
        #pragma unroll
        for (int r = 0; r < 4; r++){
            long row = row0 + q * 4 + r;
            float rr = (col < VECT) ? res[row * VECT + col] : 0.f;
            float t = (col < VECT) ? (acc[n][r] + bv + rr) : 0.f;
            acc[n][r] = t;
            sum[r] += t; sq[r] += t * t;
        }
    }
    #pragma unroll
    for (int r = 0; r < 4; r++){
        float su = sum[r], sv = sq[r];
        su += __shfl_xor(su, 1); sv += __shfl_xor(sv, 1);
        su += __shfl_xor(su, 2); sv += __shfl_xor(sv, 2);
        su += __shfl_xor(su, 4); sv += __shfl_xor(sv, 4);
        su += __shfl_xor(su, 8); sv += __shfl_xor(sv, 8);
        sum[r] = su; sq[r] = sv;
    }
    float mean[4], rstd[4];
    #pragma unroll
    for (int r = 0; r < 4; r++){
        mean[r] = sum[r] / VECT;
        float var = sq[r] / VECT - mean[r] * mean[r];
        rstd[r] = rsqrtf(var + 1e-5f);
    }
    #pragma unroll
    for (int n = 0; n < NQT; n++){
        int col = n * 16 + m;
        float gv = (col < VECT) ? g[col] : 0.f;
        float bv = (col < VECT) ? b[col] : 0.f;
        #pragma unroll
        for (int r = 0; r < 4; r++){
            long row = (long)s * SEQL + row0 + q * 4 + r;
            float t = (col < VECT) ? ((acc[n][r] - mean[r]) * rstd[r] * gv + bv) : 0.f;
            OutB[row * DP + col] = f2bf(t);
            OutF[row * DP + col] = t;
        }
    }
}

// ---------------- flash attention chunk, LDS-tiled, 2 WGs/CU (r12 config — frozen)
__global__ __launch_bounds__(256, 2) void flash_k(
    const u16* __restrict__ Q, const u16* __restrict__ K, const u16* __restrict__ VT,
    u16* __restrict__ Onum, float* __restrict__ Lp)
{
    const int tid  = threadIdx.x;
    const int lane = tid & 63;
    const int wid  = tid >> 6;
    const int bid  = blockIdx.x;
    const int s    = bid & 1;
    const int jc   = (bid >> 1) & 3;
    const int xi   = bid >> 3;
    const int row0 = xi * 64 + wid * 16;
    const int m = lane & 15, q = lane >> 4;

    __shared__ __align__(16) u16 Kt[32 * KROW];        // 21.0 KB
    __shared__ __align__(16) u16 Vt[DP * VROW];        // 25.6 KB
    __shared__ __align__(16) u16 pb[4][16 * PROW];     // 5.1 KB

    const u16* Qb = Q  + ((long)s * SEQL + row0) * DP;
    const u16* Kc = K  + (long)s * SEQL * DP + (long)jc * 1024 * DP;
    const u16* Vc = VT + (long)s * DP * SEQL + jc * 1024;

    bf16x8 qf[10];
    #pragma unroll
    for (int c = 0; c < 10; c++)
        qf[c] = *(const bf16x8*)(Qb + m * DP + c * 32 + q * 8);

    int skoff[5], wkoff[5], svoff[5], wvoff[5];
    #pragma unroll
    for (int it = 0; it < 5; it++){
        int f  = (it * 256 + tid) * 8;
        int rk = f / 320, ck = f - rk * 320;
        skoff[it] = f;
        wkoff[it] = rk * KROW + ck;
        int rv = f >> 5, cv = f & 31;
        svoff[it] = rv * SEQL + cv;
        wvoff[it] = rv * VROW + cv;
    }

    f32x4 zf = {0.f, 0.f, 0.f, 0.f};
    f32x4 oacc[NQT];
    #pragma unroll
    for (int n = 0; n < NQT; n++) oacc[n] = zf;
    float lacc[4] = {0,0,0,0};

    const float K2 = 0.057735026918962576f * L2E;
    const float MB = -16.f * L2E;

    u32x4 kreg[5], vreg[5];
    #pragma unroll
    for (int it = 0; it < 5; it++){
        kreg[it] = *(const u32x4*)(Kc + skoff[it]);
        vreg[it] = *(const u32x4*)(Vc + svoff[it]);
    }
    #pragma unroll
    for (int it = 0; it < 5; it++){
        *(u32x4*)(&Kt[wkoff[it]]) = kreg[it];
        *(u32x4*)(&Vt[wvoff[it]]) = vreg[it];
    }
    RAW_BAR();

    u16* pbw = &pb[wid][0];

    for (int j = 0; j < 32; ++j){
        if (j + 1 < 32){
            const u16* Kj = Kc + (j + 1) * 32 * DP;
            const u16* Vj = Vc + (j + 1) * 32;
            #pragma unroll
            for (int it = 0; it < 5; it++){
                kreg[it] = *(const u32x4*)(Kj + skoff[it]);
                vreg[it] = *(const u32x4*)(Vj + svoff[it]);
            }
        }
        f32x4 sA = zf, sB = zf;
        #pragma unroll
        for (int c = 0; c < 10; c++){
            bf16x8 kA = *(const bf16x8*)(&Kt[(m     ) * KROW + c * 32 + q * 8]);
            bf16x8 kB = *(const bf16x8*)(&Kt[(m + 16) * KROW + c * 32 + q * 8]);
            sA = MFMA(qf[c], kA, sA);
            sB = MFMA(qf[c], kB, sB);
        }
        #pragma unroll
        for (int r = 0; r < 4; r++){
            float a = __builtin_amdgcn_exp2f(fmaf(sA[r], K2, MB));
            float b = __builtin_amdgcn_exp2f(fmaf(sB[r], K2, MB));
            lacc[r] += a + b;
            pbw[(q * 4 + r) * PROW +      m] = f2bf(a);
            pbw[(q * 4 + r) * PROW + 16 + m] = f2bf(b);
        }
        bf16x8 pf = *(const bf16x8*)(&pbw[m * PROW + q * 8]);
        #pragma unroll
        for (int n = 0; n < NQT; n++){
            bf16x8 vb = *(const bf16x8*)(&Vt[(n * 16 + m) * VROW + q * 8]);
            oacc[n] = MFMA(pf, vb, oacc[n]);
        }
        RAW_BAR();                    // all waves done reading Kt/Vt for j
        if (j + 1 < 32){
            #pragma unroll
            for (int it = 0; it < 5; it++){
                *(u32x4*)(&Kt[wkoff[it]]) = kreg[it];
                *(u32x4*)(&Vt[wvoff[it]]) = vreg[it];
            }
        }
        RAW_BAR();                    // tiles for j+1 published
    }

    #pragma unroll
    for (int r = 0; r < 4; r++){
        float t0 = lacc[r];
        t0 += __shfl_xor(t0, 1); t0 += __shfl_xor(t0, 2);
        t0 += __shfl_xor(t0, 4); t0 += __shfl_xor(t0, 8);
        lacc[r] = t0;
    }
    const long grow0 = (long)s * SEQL + row0;
    if (m == 0){
        #pragma unroll
        for (int r = 0; r < 4; r++)
            Lp[(long)jc * 2 * SEQL + grow0 + q * 4 + r] = lacc[r];
    }
    u16* Ob = Onum + ((long)jc * 2 * SEQL + grow0) * DP;
    #pragma unroll
    for (int n = 0; n < NQT; n++)
        #pragma unroll
        for (int r = 0; r < 4; r++)
            Ob[(long)(q * 4 + r) * DP + n * 16 + m] = f2bf(oacc[n][r]);
}

// ---------------- combine chunks + LayerNorm1: out = LN(sum(Onum)/sum(l) + XF) * g + b
__global__ __launch_bounds__(256) void lncomb_k(const u16* __restrict__ Onum, const float* __restrict__ Lp,
                                                const float* __restrict__ XF,
                                                const float* __restrict__ g, const float* __restrict__ b,
                                                u16* __restrict__ OutB)
{
    long row = (long)((blockIdx.x * blockDim.x + threadIdx.x) >> 6);
    int lane = threadIdx.x & 63;
    if (row >= 2L * SEQL) return;
    float l = 0.f;
    #pragma unroll
    for (int jc = 0; jc < JC; jc++) l += Lp[(long)jc * 2 * SEQL + row];
    float inv = 1.f / l;
    const float* xr = XF + row * DP;
    float v[5], sum = 0.f, sq = 0.f;
    #pragma unroll
    for (int i = 0; i < 5; i++){
        int c = lane + i * 64;
        float o = 0.f;
        #pragma unroll
        for (int jc = 0; jc < JC; jc++)
            o += bf2f(Onum[((long)jc * 2 * SEQL + row) * DP + c]);
        float t = (c < VECT) ? (o * inv + xr[c]) : 0.f;
        v[i] = t; sum += t; sq += t * t;
    }
    #pragma unroll
    for (int o = 1; o < 64; o <<= 1){ sum += __shfl_xor(sum, o); sq += __shfl_xor(sq, o); }
    float mean = sum / VECT;
    float var  = sq / VECT - mean * mean;
    float rstd = rsqrtf(var + 1e-5f);
    #pragma unroll
    for (int i = 0; i < 5; i++){
        int c = lane + i * 64;
        float t = (c < VECT) ? ((v[i] - mean) * rstd * g[c] + b[c]) : 0.f;
        OutB[row * DP + c] = f2bf(t);
    }
}

// ---------------- GRU: 1 WG/seq, 8 waves (512 thr), ONE raw barrier/step, gates in-register.
// Wave w owns 16 h-indices; its 3 fp8 K=128 MFMA tiles are gates (r,z,n) for those
// indices -> per-wave MFMA chain depth 3 (was 6), SIMD pipe unchanged (2 waves/SIMD x 3).
// Lane: il = w*16 + q*4 + (m&3); ghr/ghz/ghn = sel4(a0/a1/a2); lanes m<4 write 1 fp8 byte.
// 128 B double-buffered h exchange; gx distance-2 register prefetch (unroll-2 sets).
__global__ __launch_bounds__(512, 1) void gru_k(
    const float* __restrict__ GXP,                         // [2][SEQL][384] fp32, permuted i*3+g
    const u8* __restrict__ Whh8p,                          // [2][384][128] fp8, 8-wave permuted
    const float* __restrict__ Bhh1, const float* __restrict__ Bhh2,
    float* __restrict__ Hout)                              // [2][128] fp32
{
    const int s = blockIdx.x;
    const int tid = threadIdx.x;
    const int lane = tid & 63;
    const int wid  = tid >> 6;                             // 0..7
    const int m = lane & 15, q = lane >> 4;
    const u8* Whh = Whh8p + (long)s * G3 * HN;
    const float* Bhh = s ? Bhh2 : Bhh1;
    const float* gx = GXP + (long)s * SEQL * G3;

    __shared__ __align__(8) u8 hst[2][HN];     // double-buffered fp8 h

    // A-frags: 3 gate-tiles, prow = wid*48 + g*16 + m, k-bytes q*32..+31
    v8i af[3];
    #pragma unroll
    for (int g = 0; g < 3; g++)
        af[g] = *(const v8i*)(Whh + (long)(wid * 48 + g * 16 + m) * HN + q * 32);

    const int rsel = m & 3;
    const int il   = wid * 16 + q * 4 + rsel;              // this lane's h index
    const int il3  = il * 3;
    const float bhr = Bhh[il], bhz = Bhh[HN + il], bhn = Bhh[2 * HN + il];

    if (tid < HN){ hst[0][tid] = 0; hst[1][tid] = 0; }

    const float* ga = gx + il3;
    float cr0 = ga[0], cz0 = ga[1], cn0 = ga[2];
    const float* gb = gx + G3 + il3;
    float cr1 = gb[0], cz1 = gb[1], cn1 = gb[2];

    __syncthreads();

    float h = 0.f;
    const f32x4 zf = {0.f, 0.f, 0.f, 0.f};

#define GRU_STEP(T, CR, CZ, CN, WB, RB)                                               \
    {                                                                                 \
        v8i bfrag = *(const v8i*)(&hst[RB][q * 32]);                                  \
        f32x4 a0 = __builtin_amdgcn_mfma_scale_f32_16x16x128_f8f6f4(af[0], bfrag, zf, 0, 0, 0, 127, 0, 127); \
        f32x4 a1 = __builtin_amdgcn_mfma_scale_f32_16x16x128_f8f6f4(af[1], bfrag, zf, 0, 0, 0, 127, 0, 127); \
        f32x4 a2 = __builtin_amdgcn_mfma_scale_f32_16x16x128_f8f6f4(af[2], bfrag, zf, 0, 0, 0, 127, 0, 127); \
        float ghr = sel4(a0, rsel);                                                   \
        float ghz = sel4(a1, rsel);                                                   \
        float ghn = sel4(a2, rsel);                                                   \
        float rg = sigm_f(CR + ghr + bhr);                                            \
        float zg = sigm_f(CZ + ghz + bhz);                                            \
        float ng = tanh_f(CN + rg * (ghn + bhn));                                     \
        h = (1.f - zg) * ng + zg * h;                                                 \
        if (m < 4){                                                                   \
            int pk = __builtin_amdgcn_cvt_pk_fp8_f32(h, h, 0, false);                 \
            hst[WB][il] = (u8)(pk & 0xFF);                                            \
        }                                                                             \
        int tp = ((T) + 2 < SEQL) ? (T) + 2 : SEQL - 1;                               \
        const float* gp = gx + (long)tp * G3 + il3;                                   \
        CR = gp[0]; CZ = gp[1]; CN = gp[2];                                           \
        asm volatile("s_waitcnt lgkmcnt(0)" ::: "memory");                            \
        __builtin_amdgcn_s_barrier();                                                 \
        asm volatile("" ::: "memory");                                                \
    }

    for (int t = 0; t < SEQL; t += 2){
        GRU_STEP(t,     cr0, cz0, cn0, 0, 1);
        GRU_STEP(t + 1, cr1, cz1, cn1, 1, 0);
    }
#undef GRU_STEP

    if (m < 4) Hout[s * HN + il] = h;
}

// ---------------- head: fc1+relu, fc2, log_softmax -> 3 fp32
__global__ __launch_bounds__(256) void final_k(const float* __restrict__ Hout,
                                               const float* __restrict__ fc1w, const float* __restrict__ fc1b,
                                               const float* __restrict__ fc2w, const float* __restrict__ fc2b,
                                               float* __restrict__ out)
{
    __shared__ float hb[256];
    __shared__ float r1[256];
    __shared__ float lg[3];
    int tid = threadIdx.x;
    hb[tid] = Hout[tid];
    __syncthreads();
    float a = 0.f;
    for (int k2 = 0; k2 < 256; k2++) a += hb[k2] * fc1w[tid * 256 + k2];
    a += fc1b[tid];
    r1[tid] = fmaxf(a, 0.f);
    __syncthreads();
    if (tid < 3){
        float v = 0.f;
        for (int k2 = 0; k2 < 256; k2++) v += r1[k2] * fc2w[tid * 256 + k2];
        lg[tid] = v + fc2b[tid];
    }
    __syncthreads();
    if (tid == 0){
        float mx = fmaxf(lg[0], fmaxf(lg[1], lg[2]));
        float se = __expf(lg[0] - mx) + __expf(lg[1] - mx) + __expf(lg[2] - mx);
        float ls = mx + logf(se);
        out[0] = lg[0] - ls;
        out[1] = lg[1] - ls;
        out[2] = lg[2] - ls;
    }
}

extern "C" void kernel_launch(void* const* d_in, const int* in_sizes, int n_in,
                              void* d_out, int out_size, void* d_ws, size_t ws_size,
                              hipStream_t stream)
{
    (void)in_sizes; (void)n_in; (void)out_size; (void)ws_size;
    const float* x1     = (const float*)d_in[0];
    const float* x2     = (const float*)d_in[1];
    const float* q_w    = (const float*)d_in[2],  *q_b   = (const float*)d_in[3];
    const float* k_w    = (const float*)d_in[4],  *k_b   = (const float*)d_in[5];
    const float* v_w    = (const float*)d_in[6],  *v_b   = (const float*)d_in[7];
    const float* aln_g  = (const float*)d_in[8],  *aln_b = (const float*)d_in[9];
    const float* w_w    = (const float*)d_in[10], *w_b   = (const float*)d_in[11];
    const float* mln_g  = (const float*)d_in[12], *mln_b = (const float*)d_in[13];
    const float* g1_wih = (const float*)d_in[14], *g1_whh = (const float*)d_in[15];
    const float* g1_bih = (const float*)d_in[16], *g1_bhh = (const float*)d_in[17];
    const float* g2_wih = (const float*)d_in[18], *g2_whh = (const float*)d_in[19];
    const float* g2_bih = (const float*)d_in[20], *g2_bhh = (const float*)d_in[21];
    const float* fc1w   = (const float*)d_in[22], *fc1b  = (const float*)d_in[23];
    const float* fc2w   = (const float*)d_in[24], *fc2b  = (const float*)d_in[25];

    char* wsp = (char*)d_ws;
    auto alloc = [&](size_t bytes) -> char* {
        char* p = wsp; wsp += (bytes + 255) & ~(size_t)255; return p;
    };
    float* XF   = (float*)alloc(2L * SEQL * DP * 4);   // fp32 stack input (residual for aln)
    u16*   CUR  = (u16*)  alloc(2L * SEQL * DP * 2);   // bf16 stack input (MFMA operand)
    u16*   Hb   = (u16*)  alloc(2L * SEQL * DP * 2);   // LN1 output bf16
    u16*   Wpk  = (u16*)  alloc(4L * DP * DP * 2);     // q,k,v,w packed bf16 [320][320]
    u16*   GWpk = (u16*)  alloc(2L * G3 * DP * 2);     // g{1,2}_wih packed bf16 [384][320]
    u8*    Whh8 = (u8*)   alloc(2L * G3 * HN);         // g{1,2}_whh fp8, 8-wave permuted rows
    float* Hout = (float*)alloc(2L * HN * 4);
    float* Lp   = (float*)alloc((long)JC * 2 * SEQL * 4);
    // union1: {QK 2 slices + VT} vs GX (permuted gate-triple layout)
    size_t u1 = (2L * 2 * SEQL * DP + 2L * DP * SEQL) * 2;
    size_t u1b = 2L * SEQL * G3 * 4;
    u16*   QKV  = (u16*)  alloc(u1 > u1b ? u1 : u1b);
    u16*   VT   = QKV + 2L * 2 * SEQL * DP;
    float* GX   = (float*)QKV;
    // union2: Onum (flash numerator partials, bf16)
    u16*   Onum = (u16*)  alloc((long)JC * 2 * SEQL * DP * 2);

    // prep (4 dispatches)
    pad_x2<<<dim3(256, 2), 256, 0, stream>>>(x1, x2, XF, CUR);
    cvt_pad_w4<<<dim3(128, 4), 256, 0, stream>>>(q_w, k_w, v_w, w_w, Wpk);
    cvt_pad_g2<<<dim3(128, 2), 256, 0, stream>>>(g1_wih, g2_wih, GWpk);
    cvt_whh2<<<dim3(192, 2), 256, 0, stream>>>(g1_whh, g2_whh, Whh8);

    for (int st = 0; st < 3; ++st){
        // Q,K -> QKV slices 0,1 ; V -> transposed at slice 2 (VT)
        gemm_k<NQT, 3, false><<<dim3(SEQL / 64, 3, 2), 256, 0, stream>>>(
            CUR, Wpk, q_b, k_b, v_b, VECT, QKV);
        flash_k<<<dim3(512), 256, 0, stream>>>(QKV, QKV + 2L*SEQL*DP, VT, Onum, Lp);
        lncomb_k<<<dim3(2 * SEQL / 4), 256, 0, stream>>>(Onum, Lp, XF, aln_g, aln_b, Hb);
        // fused: W-proj + residual(x) + LN2 -> CUR (bf16) + XF (fp32)
        gemmln_k<<<dim3(SEQL / 64, 1, 2), 256, 0, stream>>>(
            Hb, Wpk + 3L * DP * DP, w_b, x1, x2, mln_g, mln_b, CUR, XF);
    }

    // GRU input projections, gate-permuted output (weight/bias per seq) -> GX
    gemm_k<24, 4, true><<<dim3(SEQL / 64, 1, 2), 256, 0, stream>>>(
        CUR, GWpk, g1_bih, g2_bih, nullptr, G3, GX);
    gru_k<<<dim3(2), 512, 0, stream>>>(GX, Whh8, g1_bhh, g2_bhh, Hout);
    final_k<<<dim3(1), 256, 0, stream>>>(Hout, fc1w, fc1b, fc2w, fc2b, (float*)d_out);
}